// Round 1
// 1117.483 us; speedup vs baseline: 1.8433x; 1.8433x over previous
//
#include <hip/hip_runtime.h>
#include <hip/hip_bf16.h>
#include <stdint.h>

#define PS 56
#define S_ 3136
#define DIM 128
#define NTOK 200704   // 64 * 3136

typedef __attribute__((ext_vector_type(8))) short short8;
typedef __attribute__((ext_vector_type(4))) float f32x4;

__device__ __forceinline__ float bflo(uint32_t u){ return __uint_as_float(u << 16); }
__device__ __forceinline__ float bfhi(uint32_t u){ return __uint_as_float(u & 0xffff0000u); }
__device__ __forceinline__ uint32_t bfpack(float a, float b){
  uint32_t ua = __float_as_uint(a); ua = (ua + 0x7fffu + ((ua >> 16) & 1u)) >> 16;
  uint32_t ub = __float_as_uint(b); ub = (ub + 0x7fffu + ((ub >> 16) & 1u)) & 0xffff0000u;
  return ua | ub;
}
__device__ __forceinline__ uint16_t bf16of(float a){
  uint32_t ua = __float_as_uint(a);
  return (uint16_t)((ua + 0x7fffu + ((ua >> 16) & 1u)) >> 16);
}

__device__ __forceinline__ int win_map(int r, int shift) {
  int b = r / S_;
  int rem = r - b * S_;
  int w = rem / 49;
  int p = rem - w * 49;
  int i = p / 7, j = p - i * 7;
  int wr = w >> 3, wc = w & 7;
  int row = wr * 7 + i + shift; if (row >= PS) row -= PS;
  int col = wc * 7 + j + shift; if (col >= PS) col -= PS;
  return b * S_ + row * PS + col;
}

__global__ __launch_bounds__(256) void stats_k(const float* __restrict__ X, float* __restrict__ st) {
  int t = blockIdx.x * 4 + (threadIdx.x >> 6);
  int lane = threadIdx.x & 63;
  float2 v = *(const float2*)(X + (size_t)t * DIM + lane * 2);
  float s = v.x + v.y, sq = v.x * v.x + v.y * v.y;
  #pragma unroll
  for (int o = 32; o; o >>= 1) { s += __shfl_xor(s, o); sq += __shfl_xor(sq, o); }
  if (lane == 0) {
    float mu = s * (1.0f / 128.0f);
    float var = sq * (1.0f / 128.0f) - mu * mu;
    st[2 * t] = mu;
    st[2 * t + 1] = rsqrtf(var + 1e-5f);
  }
}

// ================= VALU GEMM — VERBATIM (known-good) =================
constexpr int VTM = 64, VTN = 128, VKC = 64, VKSTR = VKC + 4;

template<int IN_MODE, int IN_SHIFT, int OUT_SHIFT, bool RES, bool OUT_BF16>
__global__ __launch_bounds__(256) void gemm_v(
    const void* __restrict__ Asrc, const float* __restrict__ st,
    const float* __restrict__ lng, const float* __restrict__ lnb,
    const float* __restrict__ W, const float* __restrict__ bias,
    const float* __restrict__ Rsrc, void* __restrict__ Out, int Ncols)
{
  __shared__ float As[VTM][VKSTR];
  __shared__ float Ws[VTN][VKSTR];
  const int tid = threadIdx.x;
  const int tx = tid & 15, ty = tid >> 4;
  const int ty4 = ty * 4;
  const int mtile = blockIdx.y * VTM;
  const int ntile = blockIdx.x * VTN;
  float acc[4][8];
  #pragma unroll
  for (int r = 0; r < 4; ++r)
    #pragma unroll
    for (int c = 0; c < 8; ++c) acc[r][c] = 0.f;

  for (int kc = 0; kc < DIM; kc += VKC) {
    #pragma unroll
    for (int it = 0; it < 4; ++it) {
      int idx = tid + it * 256;
      int m = idx >> 4;
      int k4 = (idx & 15) << 2;
      int gm = mtile + m;
      float4 a;
      if constexpr (IN_MODE == 0) {
        int src = (IN_SHIFT < 0) ? gm : win_map(gm, IN_SHIFT);
        a = *(const float4*)((const float*)Asrc + (size_t)src * DIM + kc + k4);
        float mu = st[2 * src], rs = st[2 * src + 1];
        int k = kc + k4;
        a.x = (a.x - mu) * rs * lng[k]     + lnb[k];
        a.y = (a.y - mu) * rs * lng[k + 1] + lnb[k + 1];
        a.z = (a.z - mu) * rs * lng[k + 2] + lnb[k + 2];
        a.w = (a.w - mu) * rs * lng[k + 3] + lnb[k + 3];
      } else {
        const uint32_t* ap = (const uint32_t*)((const uint16_t*)Asrc + (size_t)gm * DIM + kc + k4);
        uint32_t u0 = ap[0], u1 = ap[1];
        a.x = bflo(u0); a.y = bfhi(u0); a.z = bflo(u1); a.w = bfhi(u1);
      }
      *(float4*)&As[m][k4] = a;
    }
    #pragma unroll
    for (int it = 0; it < 8; ++it) {
      int idx = tid + it * 256;
      int n = idx >> 4;
      int k4 = (idx & 15) << 2;
      float4 w = *(const float4*)(W + (size_t)(ntile + n) * DIM + kc + k4);
      *(float4*)&Ws[n][k4] = w;
    }
    __syncthreads();
    #pragma unroll 4
    for (int k = 0; k < VKC; k += 2) {
      float2 a0 = *(const float2*)&As[ty4 + 0][k];
      float2 a1 = *(const float2*)&As[ty4 + 1][k];
      float2 a2 = *(const float2*)&As[ty4 + 2][k];
      float2 a3 = *(const float2*)&As[ty4 + 3][k];
      #pragma unroll
      for (int c = 0; c < 8; ++c) {
        float2 w = *(const float2*)&Ws[tx + 16 * c][k];
        acc[0][c] = fmaf(a0.x, w.x, acc[0][c]);
        acc[1][c] = fmaf(a1.x, w.x, acc[1][c]);
        acc[2][c] = fmaf(a2.x, w.x, acc[2][c]);
        acc[3][c] = fmaf(a3.x, w.x, acc[3][c]);
        acc[0][c] = fmaf(a0.y, w.y, acc[0][c]);
        acc[1][c] = fmaf(a1.y, w.y, acc[1][c]);
        acc[2][c] = fmaf(a2.y, w.y, acc[2][c]);
        acc[3][c] = fmaf(a3.y, w.y, acc[3][c]);
      }
    }
    __syncthreads();
  }
  float bb[8];
  #pragma unroll
  for (int c = 0; c < 8; ++c) bb[c] = bias[ntile + tx + 16 * c];
  #pragma unroll
  for (int r = 0; r < 4; ++r) {
    int gm = mtile + ty4 + r;
    int orow = (OUT_SHIFT < 0) ? gm : win_map(gm, OUT_SHIFT);
    #pragma unroll
    for (int c = 0; c < 8; ++c) {
      int gn = ntile + tx + 16 * c;
      float v = acc[r][c] + bb[c];
      if constexpr (RES) v += Rsrc[(size_t)orow * DIM + gn];
      if constexpr (OUT_BF16) ((uint16_t*)Out)[(size_t)gm * Ncols + gn] = bf16of(v);
      else                    ((float*)Out)[(size_t)orow * (size_t)Ncols + gn] = v;
    }
  }
}

// ================= MFMA GEMM — VERBATIM (known-good, used for qkv) =================
constexpr int MKC = 64, MKSTR = MKC + 8;

template<int IN_MODE, int IN_SHIFT, int OUT_SHIFT, bool RES, bool OUT_BF16>
__global__ __launch_bounds__(256) void gemm_m(
    const void* __restrict__ Asrc, const float* __restrict__ st,
    const float* __restrict__ lng, const float* __restrict__ lnb,
    const float* __restrict__ W, const float* __restrict__ bias,
    const float* Rsrc, void* Out, int Ncols)
{
  __shared__ __align__(16) uint16_t As[128][MKSTR];
  __shared__ __align__(16) uint16_t Ws[128][MKSTR];
  const int tid = threadIdx.x;
  const int lane = tid & 63;
  const int lanelow = lane & 15;
  const int quad = lane >> 4;
  const int wid = tid >> 6;
  const int wave_m = wid >> 1, wave_n = wid & 1;
  const int mtile = blockIdx.y * 128;
  const int ntile = blockIdx.x * 128;

  f32x4 acc[4][4];
  #pragma unroll
  for (int mt = 0; mt < 4; ++mt)
    #pragma unroll
    for (int nt = 0; nt < 4; ++nt) acc[mt][nt] = (f32x4){0.f, 0.f, 0.f, 0.f};

  for (int kc = 0; kc < DIM; kc += MKC) {
    #pragma unroll
    for (int it = 0; it < 8; ++it) {
      int idx = tid + it * 256;
      int m = idx >> 4;
      int k4 = (idx & 15) << 2;
      int gm = mtile + m;
      uint2 packed;
      if constexpr (IN_MODE == 0) {
        int src = (IN_SHIFT < 0) ? gm : win_map(gm, IN_SHIFT);
        float4 a = *(const float4*)((const float*)Asrc + (size_t)src * DIM + kc + k4);
        float mu = st[2 * src], rs = st[2 * src + 1];
        int k = kc + k4;
        a.x = (a.x - mu) * rs * lng[k]     + lnb[k];
        a.y = (a.y - mu) * rs * lng[k + 1] + lnb[k + 1];
        a.z = (a.z - mu) * rs * lng[k + 2] + lnb[k + 2];
        a.w = (a.w - mu) * rs * lng[k + 3] + lnb[k + 3];
        packed.x = bfpack(a.x, a.y);
        packed.y = bfpack(a.z, a.w);
      } else {
        packed = *(const uint2*)((const uint16_t*)Asrc + (size_t)gm * DIM + kc + k4);
      }
      *(uint2*)&As[m][k4] = packed;
    }
    #pragma unroll
    for (int it = 0; it < 8; ++it) {
      int idx = tid + it * 256;
      int n = idx >> 4;
      int k4 = (idx & 15) << 2;
      float4 w = *(const float4*)(W + (size_t)(ntile + n) * DIM + kc + k4);
      uint2 packed;
      packed.x = bfpack(w.x, w.y);
      packed.y = bfpack(w.z, w.w);
      *(uint2*)&Ws[n][k4] = packed;
    }
    __syncthreads();
    #pragma unroll
    for (int k0 = 0; k0 < MKC; k0 += 32) {
      short8 af[4], bf[4];
      #pragma unroll
      for (int mt = 0; mt < 4; ++mt)
        af[mt] = *(const short8*)&As[wave_m * 64 + mt * 16 + lanelow][k0 + quad * 8];
      #pragma unroll
      for (int nt = 0; nt < 4; ++nt)
        bf[nt] = *(const short8*)&Ws[wave_n * 64 + nt * 16 + lanelow][k0 + quad * 8];
      #pragma unroll
      for (int mt = 0; mt < 4; ++mt)
        #pragma unroll
        for (int nt = 0; nt < 4; ++nt)
          acc[mt][nt] = __builtin_amdgcn_mfma_f32_16x16x32_bf16(af[mt], bf[nt], acc[mt][nt], 0, 0, 0);
    }
    __syncthreads();
  }
  #pragma unroll
  for (int nt = 0; nt < 4; ++nt) {
    int col = ntile + wave_n * 64 + nt * 16 + lanelow;
    float bb = bias[col];
    #pragma unroll
    for (int mt = 0; mt < 4; ++mt) {
      #pragma unroll
      for (int r = 0; r < 4; ++r) {
        int gm = mtile + wave_m * 64 + mt * 16 + quad * 4 + r;
        float v = acc[mt][nt][r] + bb;
        if constexpr (OUT_BF16) {
          ((uint16_t*)Out)[(size_t)gm * Ncols + col] = bf16of(v);
        } else {
          int orow = (OUT_SHIFT < 0) ? gm : win_map(gm, OUT_SHIFT);
          if constexpr (RES) v += Rsrc[(size_t)orow * DIM + col];
          ((float*)Out)[(size_t)orow * (size_t)Ncols + col] = v;
        }
      }
    }
  }
}

// ================= bias precompute: biasT[h][k][q], 64x64 padded, mask baked =================
__global__ __launch_bounds__(256) void bias_k(const float* __restrict__ tbl, float* __restrict__ biasT) {
  int idx = blockIdx.x * 256 + threadIdx.x;   // 0..16383  (h<<12 | k<<6 | q)
  int h = idx >> 12;
  int k = (idx >> 6) & 63;
  int q = idx & 63;
  float v;
  if (k >= 49)      v = -1e30f;      // padded key -> softmax weight 0
  else if (q >= 49) v = 0.f;         // padded query row: never stored, keep finite
  else {
    int yi = q / 7, xi = q - yi * 7; // i = query
    int yj = k / 7, xj = k - yj * 7; // j = key
    v = tbl[((yi - yj + 6) * 13 + (xi - xj + 6)) * 4 + h];
  }
  biasT[idx] = v;
}

// ================= MFMA attention: 1 block = 1 window, wave h = head h =================
// S^T = K·Q^T (A=K,B=Q same fragment convention as verified gemm_m), softmax over k
// = in-lane(16) + shfl_xor(16,32); P->bf16 via per-wave LDS transpose; O = P·V.
constexpr int QKV_STR = 392;   // 384 + 8 bf16 pad: lane stride 196 dwords ≡ 4 (mod 32) -> clean b128
constexpr int P_STR   = 72;    // 64 + 8 bf16 pad: 36 dwords ≡ 4 (mod 32)

__global__ __launch_bounds__(256) void attn_m(const uint16_t* __restrict__ qkv,
                                              const float* __restrict__ biasT,
                                              uint16_t* __restrict__ aw)
{
  __shared__ __align__(16) uint16_t qs[49 * QKV_STR];   // 38,416 B: window's qkv rows
  __shared__ __align__(16) uint16_t ps[4][64 * P_STR];  // 36,864 B: per-wave P[q][k]
  const int tid = threadIdx.x;
  const int lane = tid & 63;
  const int h = tid >> 6;            // wave = head
  const int lanelow = lane & 15;
  const int quad = lane >> 4;
  const int base = blockIdx.x * 49;  // 4096 windows

  // stage 49 rows x 384 bf16, coalesced 16B chunks (49*48 = 2352 chunks)
  for (int c = tid; c < 2352; c += 256) {
    int row = c / 48;
    int col = (c - row * 48) * 8;
    *(float4*)(qs + row * QKV_STR + col) =
        *(const float4*)(qkv + (size_t)(base + row) * 384 + col);
  }
  __syncthreads();

  // ---- S^T = K·Q^T : C[k_tok][q_tok], rows k = kt*16+quad*4+r, cols q = qt*16+lanelow ----
  f32x4 sc[4][4];
  #pragma unroll
  for (int kt = 0; kt < 4; ++kt)
    #pragma unroll
    for (int qt = 0; qt < 4; ++qt) sc[kt][qt] = (f32x4){0.f, 0.f, 0.f, 0.f};
  {
    short8 kf[4], qf[4];
    const int kcol = 128 + h * 32 + quad * 8;
    const int qcol = h * 32 + quad * 8;
    #pragma unroll
    for (int t = 0; t < 4; ++t) {
      int tok = t * 16 + lanelow; if (tok > 48) tok = 48;   // clamp pad -> masked later
      kf[t] = *(const short8*)(qs + tok * QKV_STR + kcol);
      qf[t] = *(const short8*)(qs + tok * QKV_STR + qcol);
    }
    #pragma unroll
    for (int kt = 0; kt < 4; ++kt)
      #pragma unroll
      for (int qt = 0; qt < 4; ++qt)
        sc[kt][qt] = __builtin_amdgcn_mfma_f32_16x16x32_bf16(kf[kt], qf[qt], sc[kt][qt], 0, 0, 0);
  }

  // ---- scale + bias (mask baked in biasT), softmax over k per q-column ----
  const float* bh = biasT + h * 4096;
  #pragma unroll
  for (int kt = 0; kt < 4; ++kt)
    #pragma unroll
    for (int r = 0; r < 4; ++r) {
      const float* br = bh + (kt * 16 + quad * 4 + r) * 64 + lanelow;
      #pragma unroll
      for (int qt = 0; qt < 4; ++qt)
        sc[kt][qt][r] = fmaf(sc[kt][qt][r], 0.17677669529663689f, br[qt * 16]);
    }
  #pragma unroll
  for (int qt = 0; qt < 4; ++qt) {
    float m = sc[0][qt][0];
    #pragma unroll
    for (int kt = 0; kt < 4; ++kt)
      #pragma unroll
      for (int r = 0; r < 4; ++r) m = fmaxf(m, sc[kt][qt][r]);
    m = fmaxf(m, __shfl_xor(m, 16));
    m = fmaxf(m, __shfl_xor(m, 32));
    float s = 0.f;
    #pragma unroll
    for (int kt = 0; kt < 4; ++kt)
      #pragma unroll
      for (int r = 0; r < 4; ++r) {
        float e = __expf(sc[kt][qt][r] - m);
        sc[kt][qt][r] = e;
        s += e;
      }
    s += __shfl_xor(s, 16);
    s += __shfl_xor(s, 32);
    float inv = 1.0f / s;
    #pragma unroll
    for (int kt = 0; kt < 4; ++kt)
      #pragma unroll
      for (int r = 0; r < 4; ++r) sc[kt][qt][r] *= inv;
  }

  // ---- P (bf16) -> per-wave LDS as P[q][k] (transpose of C layout) ----
  uint16_t* pw = &ps[h][0];
  #pragma unroll
  for (int qt = 0; qt < 4; ++qt)
    #pragma unroll
    for (int kt = 0; kt < 4; ++kt) {
      uint2 pk;
      pk.x = bfpack(sc[kt][qt][0], sc[kt][qt][1]);
      pk.y = bfpack(sc[kt][qt][2], sc[kt][qt][3]);
      *(uint2*)(pw + (qt * 16 + lanelow) * P_STR + kt * 16 + quad * 4) = pk;
    }

  // ---- O = P·V : A = P[q][k] (b128 from own LDS), B[d][k] = V[k][d] (b16 gathers) ----
  f32x4 oc[4][2];
  #pragma unroll
  for (int qt = 0; qt < 4; ++qt)
    #pragma unroll
    for (int dt = 0; dt < 2; ++dt) oc[qt][dt] = (f32x4){0.f, 0.f, 0.f, 0.f};
  short8 pf[4][2];
  #pragma unroll
  for (int qt = 0; qt < 4; ++qt)
    #pragma unroll
    for (int kp = 0; kp < 2; ++kp)
      pf[qt][kp] = *(const short8*)(pw + (qt * 16 + lanelow) * P_STR + kp * 32 + quad * 8);
  short8 vf[2][2];
  #pragma unroll
  for (int dt = 0; dt < 2; ++dt)
    #pragma unroll
    for (int kp = 0; kp < 2; ++kp) {
      short8 b;
      #pragma unroll
      for (int j = 0; j < 8; ++j) {
        int tok = kp * 32 + quad * 8 + j; if (tok > 48) tok = 48;  // P=0 there anyway
        b[j] = (short)qs[tok * QKV_STR + 256 + h * 32 + dt * 16 + lanelow];
      }
      vf[dt][kp] = b;
    }
  #pragma unroll
  for (int qt = 0; qt < 4; ++qt)
    #pragma unroll
    for (int dt = 0; dt < 2; ++dt)
      #pragma unroll
      for (int kp = 0; kp < 2; ++kp)
        oc[qt][dt] = __builtin_amdgcn_mfma_f32_16x16x32_bf16(pf[qt][kp], vf[dt][kp], oc[qt][dt], 0, 0, 0);

  // ---- epilogue: O rows q = qt*16+quad*4+r, cols d = dt*16+lanelow ----
  #pragma unroll
  for (int qt = 0; qt < 4; ++qt)
    #pragma unroll
    for (int r = 0; r < 4; ++r) {
      int q = qt * 16 + quad * 4 + r;
      if (q < 49) {
        uint16_t* dst = aw + (size_t)(base + q) * 128 + h * 32 + lanelow;
        dst[0]  = bf16of(oc[qt][0][r]);
        dst[16] = bf16of(oc[qt][1][r]);
      }
    }
}

extern "C" void kernel_launch(void* const* d_in, const int* in_sizes, int n_in,
                              void* d_out, int out_size, void* d_ws, size_t ws_size,
                              hipStream_t stream) {
  const float* x0    = (const float*)d_in[0];
  const float* ln1g  = (const float*)d_in[1];
  const float* ln1b  = (const float*)d_in[2];
  const float* wqkv1 = (const float*)d_in[3];
  const float* bqkv1 = (const float*)d_in[4];
  const float* wo1   = (const float*)d_in[5];
  const float* bo1   = (const float*)d_in[6];
  const float* tbl1  = (const float*)d_in[7];
  const float* ln2g  = (const float*)d_in[8];
  const float* ln2b  = (const float*)d_in[9];
  const float* wm1   = (const float*)d_in[10];
  const float* bm1   = (const float*)d_in[11];
  const float* ln3g  = (const float*)d_in[12];
  const float* ln3b  = (const float*)d_in[13];
  const float* wqkv2 = (const float*)d_in[14];
  const float* bqkv2 = (const float*)d_in[15];
  const float* wo2   = (const float*)d_in[16];
  const float* bo2   = (const float*)d_in[17];
  const float* tbl2  = (const float*)d_in[18];
  const float* ln4g  = (const float*)d_in[19];
  const float* ln4b  = (const float*)d_in[20];
  const float* wm2   = (const float*)d_in[21];
  const float* bm2   = (const float*)d_in[22];

  char* ws = (char*)d_ws;
  size_t off = 0;
  float* st = (float*)(ws + off);         off += (size_t)NTOK * 2 * sizeof(float);
  off = (off + 255) & ~(size_t)255;
  uint16_t* qkvb = (uint16_t*)(ws + off); off += (size_t)NTOK * 384 * sizeof(uint16_t);
  uint16_t* awb  = (uint16_t*)(ws + off); off += (size_t)NTOK * 128 * sizeof(uint16_t);
  float* x2      = (float*)(ws + off);    off += (size_t)NTOK * 128 * sizeof(float);
  float* biasT1  = (float*)(ws + off);    off += 16384 * sizeof(float);
  float* biasT2  = (float*)(ws + off);    off += 16384 * sizeof(float);
  if (ws_size < off) return;
  float* x1 = (float*)d_out;

  dim3 blk(256);
  dim3 sgrid(NTOK / 4);
  dim3 g3m(3, 1568);        // MFMA qkv tiles (128-row)
  dim3 g1v(1, 3136);        // VALU tiles (64-row)
  dim3 agrid(4096);         // one block per window, 4 waves = 4 heads

  // bias tables (tiny, L2-resident; mask for padded keys baked in)
  bias_k<<<64, blk, 0, stream>>>(tbl1, biasT1);
  bias_k<<<64, blk, 0, stream>>>(tbl2, biasT2);

  // block 1: W-MSA
  stats_k<<<sgrid, blk, 0, stream>>>(x0, st);
  gemm_m<0, 0, -1, false, true><<<g3m, blk, 0, stream>>>(x0, st, ln1g, ln1b, wqkv1, bqkv1, nullptr, qkvb, 384);
  attn_m<<<agrid, blk, 0, stream>>>(qkvb, biasT1, awb);
  gemm_v<1, -1, -1, true, false><<<g1v, blk, 0, stream>>>(awb, nullptr, nullptr, nullptr, wo1, bo1, x0, x1, 128);
  // mlp1
  stats_k<<<sgrid, blk, 0, stream>>>(x1, st);
  gemm_v<0, -1, -1, true, false><<<g1v, blk, 0, stream>>>(x1, st, ln2g, ln2b, wm1, bm1, x1, x2, 128);
  // block 2: SW-MSA
  stats_k<<<sgrid, blk, 0, stream>>>(x2, st);
  gemm_m<0, 3, -1, false, true><<<g3m, blk, 0, stream>>>(x2, st, ln3g, ln3b, wqkv2, bqkv2, nullptr, qkvb, 384);
  attn_m<<<agrid, blk, 0, stream>>>(qkvb, biasT2, awb);
  gemm_v<1, -1, 3, true, false><<<g1v, blk, 0, stream>>>(awb, nullptr, nullptr, nullptr, wo2, bo2, x2, x2, 128);
  // mlp2
  stats_k<<<sgrid, blk, 0, stream>>>(x2, st);
  gemm_v<0, -1, -1, false, false><<<g1v, blk, 0, stream>>>(x2, st, ln4g, ln4b, wm2, bm2, nullptr, d_out, 128);
}

// Round 2
// 1048.908 us; speedup vs baseline: 1.9638x; 1.0654x over previous
//
#include <hip/hip_runtime.h>
#include <hip/hip_bf16.h>
#include <stdint.h>

#define PS 56
#define S_ 3136
#define DIM 128
#define NTOK 200704   // 64 * 3136

typedef __attribute__((ext_vector_type(8))) short short8;
typedef __attribute__((ext_vector_type(4))) float f32x4;

__device__ __forceinline__ float bflo(uint32_t u){ return __uint_as_float(u << 16); }
__device__ __forceinline__ float bfhi(uint32_t u){ return __uint_as_float(u & 0xffff0000u); }
__device__ __forceinline__ uint32_t bfpack(float a, float b){
  uint32_t ua = __float_as_uint(a); ua = (ua + 0x7fffu + ((ua >> 16) & 1u)) >> 16;
  uint32_t ub = __float_as_uint(b); ub = (ub + 0x7fffu + ((ub >> 16) & 1u)) & 0xffff0000u;
  return ua | ub;
}
__device__ __forceinline__ uint16_t bf16of(float a){
  uint32_t ua = __float_as_uint(a);
  return (uint16_t)((ua + 0x7fffu + ((ua >> 16) & 1u)) >> 16);
}

__device__ __forceinline__ int win_map(int r, int shift) {
  int b = r / S_;
  int rem = r - b * S_;
  int w = rem / 49;
  int p = rem - w * 49;
  int i = p / 7, j = p - i * 7;
  int wr = w >> 3, wc = w & 7;
  int row = wr * 7 + i + shift; if (row >= PS) row -= PS;
  int col = wc * 7 + j + shift; if (col >= PS) col -= PS;
  return b * S_ + row * PS + col;
}

// ===== LN fused to bf16: one wave per token, writes normalized bf16 row =====
__global__ __launch_bounds__(256) void ln_k(const float* __restrict__ X,
                                            const float* __restrict__ g,
                                            const float* __restrict__ b,
                                            uint16_t* __restrict__ O) {
  int t = blockIdx.x * 4 + (threadIdx.x >> 6);
  int lane = threadIdx.x & 63;
  float2 v = *(const float2*)(X + (size_t)t * DIM + lane * 2);
  float s = v.x + v.y, sq = v.x * v.x + v.y * v.y;
  #pragma unroll
  for (int o = 32; o; o >>= 1) { s += __shfl_xor(s, o); sq += __shfl_xor(sq, o); }
  float mu = s * (1.0f / 128.0f);
  float rs = rsqrtf(sq * (1.0f / 128.0f) - mu * mu + 1e-5f);
  float2 gg = *(const float2*)(g + lane * 2);
  float2 bb = *(const float2*)(b + lane * 2);
  float a = (v.x - mu) * rs * gg.x + bb.x;
  float c = (v.y - mu) * rs * gg.y + bb.y;
  ((uint32_t*)O)[(size_t)t * 64 + lane] = bfpack(a, c);
}

// ===== one-shot weight conversion f32 -> bf16 (6 arrays, fixed segments) =====
__global__ __launch_bounds__(256) void wconv_k(
    const float* __restrict__ w0, const float* __restrict__ w1,
    const float* __restrict__ w2, const float* __restrict__ w3,
    const float* __restrict__ w4, const float* __restrict__ w5,
    uint16_t* __restrict__ out) {
  int i = blockIdx.x * 256 + threadIdx.x;   // 0..163839
  float v;
  if      (i <  49152) v = w0[i];
  else if (i <  98304) v = w1[i -  49152];
  else if (i < 114688) v = w2[i -  98304];
  else if (i < 131072) v = w3[i - 114688];
  else if (i < 147456) v = w4[i - 131072];
  else                 v = w5[i - 147456];
  out[i] = bf16of(v);
}

// ================= MFMA GEMM — verified fragment layout, pure-bf16 staging =================
constexpr int MKC = 64, MKSTR = MKC + 8;

template<int IN_SHIFT, int OUT_SHIFT, bool RES, bool OUT_BF16>
__global__ __launch_bounds__(256) void gemm_m2(
    const uint16_t* __restrict__ A, const uint16_t* __restrict__ Wb,
    const float* __restrict__ bias, const float* __restrict__ Rsrc,
    void* __restrict__ Out, int Ncols)
{
  __shared__ __align__(16) uint16_t As[128][MKSTR];
  __shared__ __align__(16) uint16_t Ws[128][MKSTR];
  const int tid = threadIdx.x;
  const int lane = tid & 63;
  const int lanelow = lane & 15;
  const int quad = lane >> 4;
  const int wid = tid >> 6;
  const int wave_m = wid >> 1, wave_n = wid & 1;
  const int mtile = blockIdx.y * 128;
  const int ntile = blockIdx.x * 128;

  f32x4 acc[4][4];
  #pragma unroll
  for (int mt = 0; mt < 4; ++mt)
    #pragma unroll
    for (int nt = 0; nt < 4; ++nt) acc[mt][nt] = (f32x4){0.f, 0.f, 0.f, 0.f};

  for (int kc = 0; kc < DIM; kc += MKC) {
    #pragma unroll
    for (int it = 0; it < 8; ++it) {
      int idx = tid + it * 256;
      int m = idx >> 4;
      int k4 = (idx & 15) << 2;
      int gm = mtile + m;
      int src = (IN_SHIFT < 0) ? gm : win_map(gm, IN_SHIFT);
      *(uint2*)&As[m][k4] = *(const uint2*)(A + (size_t)src * DIM + kc + k4);
    }
    #pragma unroll
    for (int it = 0; it < 8; ++it) {
      int idx = tid + it * 256;
      int n = idx >> 4;
      int k4 = (idx & 15) << 2;
      *(uint2*)&Ws[n][k4] = *(const uint2*)(Wb + (size_t)(ntile + n) * DIM + kc + k4);
    }
    __syncthreads();
    #pragma unroll
    for (int k0 = 0; k0 < MKC; k0 += 32) {
      short8 af[4], bf[4];
      #pragma unroll
      for (int mt = 0; mt < 4; ++mt)
        af[mt] = *(const short8*)&As[wave_m * 64 + mt * 16 + lanelow][k0 + quad * 8];
      #pragma unroll
      for (int nt = 0; nt < 4; ++nt)
        bf[nt] = *(const short8*)&Ws[wave_n * 64 + nt * 16 + lanelow][k0 + quad * 8];
      #pragma unroll
      for (int mt = 0; mt < 4; ++mt)
        #pragma unroll
        for (int nt = 0; nt < 4; ++nt)
          acc[mt][nt] = __builtin_amdgcn_mfma_f32_16x16x32_bf16(af[mt], bf[nt], acc[mt][nt], 0, 0, 0);
    }
    __syncthreads();
  }
  #pragma unroll
  for (int nt = 0; nt < 4; ++nt) {
    int col = ntile + wave_n * 64 + nt * 16 + lanelow;
    float bb = bias[col];
    #pragma unroll
    for (int mt = 0; mt < 4; ++mt) {
      #pragma unroll
      for (int r = 0; r < 4; ++r) {
        int gm = mtile + wave_m * 64 + mt * 16 + quad * 4 + r;
        float v = acc[mt][nt][r] + bb;
        if constexpr (OUT_BF16) {
          ((uint16_t*)Out)[(size_t)gm * Ncols + col] = bf16of(v);
        } else {
          int orow = (OUT_SHIFT < 0) ? gm : win_map(gm, OUT_SHIFT);
          if constexpr (RES) v += Rsrc[(size_t)orow * DIM + col];
          ((float*)Out)[(size_t)orow * (size_t)Ncols + col] = v;
        }
      }
    }
  }
}

// ================= bias precompute: biasT[h][k][q], 64x64 padded, mask baked =================
__global__ __launch_bounds__(256) void bias_k(const float* __restrict__ tbl, float* __restrict__ biasT) {
  int idx = blockIdx.x * 256 + threadIdx.x;   // 0..16383  (h<<12 | k<<6 | q)
  int h = idx >> 12;
  int k = (idx >> 6) & 63;
  int q = idx & 63;
  float v;
  if (k >= 49)      v = -1e30f;      // padded key -> softmax weight 0
  else if (q >= 49) v = 0.f;         // padded query row: never stored, keep finite
  else {
    int yi = q / 7, xi = q - yi * 7; // i = query
    int yj = k / 7, xj = k - yj * 7; // j = key
    v = tbl[((yi - yj + 6) * 13 + (xi - xj + 6)) * 4 + h];
  }
  biasT[idx] = v;
}

// ================= MFMA attention — VERBATIM (known-good) =================
constexpr int QKV_STR = 392;
constexpr int P_STR   = 72;

__global__ __launch_bounds__(256) void attn_m(const uint16_t* __restrict__ qkv,
                                              const float* __restrict__ biasT,
                                              uint16_t* __restrict__ aw)
{
  __shared__ __align__(16) uint16_t qs[49 * QKV_STR];
  __shared__ __align__(16) uint16_t ps[4][64 * P_STR];
  const int tid = threadIdx.x;
  const int lane = tid & 63;
  const int h = tid >> 6;
  const int lanelow = lane & 15;
  const int quad = lane >> 4;
  const int base = blockIdx.x * 49;

  for (int c = tid; c < 2352; c += 256) {
    int row = c / 48;
    int col = (c - row * 48) * 8;
    *(float4*)(qs + row * QKV_STR + col) =
        *(const float4*)(qkv + (size_t)(base + row) * 384 + col);
  }
  __syncthreads();

  f32x4 sc[4][4];
  #pragma unroll
  for (int kt = 0; kt < 4; ++kt)
    #pragma unroll
    for (int qt = 0; qt < 4; ++qt) sc[kt][qt] = (f32x4){0.f, 0.f, 0.f, 0.f};
  {
    short8 kf[4], qf[4];
    const int kcol = 128 + h * 32 + quad * 8;
    const int qcol = h * 32 + quad * 8;
    #pragma unroll
    for (int t = 0; t < 4; ++t) {
      int tok = t * 16 + lanelow; if (tok > 48) tok = 48;
      kf[t] = *(const short8*)(qs + tok * QKV_STR + kcol);
      qf[t] = *(const short8*)(qs + tok * QKV_STR + qcol);
    }
    #pragma unroll
    for (int kt = 0; kt < 4; ++kt)
      #pragma unroll
      for (int qt = 0; qt < 4; ++qt)
        sc[kt][qt] = __builtin_amdgcn_mfma_f32_16x16x32_bf16(kf[kt], qf[qt], sc[kt][qt], 0, 0, 0);
  }

  const float* bh = biasT + h * 4096;
  #pragma unroll
  for (int kt = 0; kt < 4; ++kt)
    #pragma unroll
    for (int r = 0; r < 4; ++r) {
      const float* br = bh + (kt * 16 + quad * 4 + r) * 64 + lanelow;
      #pragma unroll
      for (int qt = 0; qt < 4; ++qt)
        sc[kt][qt][r] = fmaf(sc[kt][qt][r], 0.17677669529663689f, br[qt * 16]);
    }
  #pragma unroll
  for (int qt = 0; qt < 4; ++qt) {
    float m = sc[0][qt][0];
    #pragma unroll
    for (int kt = 0; kt < 4; ++kt)
      #pragma unroll
      for (int r = 0; r < 4; ++r) m = fmaxf(m, sc[kt][qt][r]);
    m = fmaxf(m, __shfl_xor(m, 16));
    m = fmaxf(m, __shfl_xor(m, 32));
    float s = 0.f;
    #pragma unroll
    for (int kt = 0; kt < 4; ++kt)
      #pragma unroll
      for (int r = 0; r < 4; ++r) {
        float e = __expf(sc[kt][qt][r] - m);
        sc[kt][qt][r] = e;
        s += e;
      }
    s += __shfl_xor(s, 16);
    s += __shfl_xor(s, 32);
    float inv = 1.0f / s;
    #pragma unroll
    for (int kt = 0; kt < 4; ++kt)
      #pragma unroll
      for (int r = 0; r < 4; ++r) sc[kt][qt][r] *= inv;
  }

  uint16_t* pw = &ps[h][0];
  #pragma unroll
  for (int qt = 0; qt < 4; ++qt)
    #pragma unroll
    for (int kt = 0; kt < 4; ++kt) {
      uint2 pk;
      pk.x = bfpack(sc[kt][qt][0], sc[kt][qt][1]);
      pk.y = bfpack(sc[kt][qt][2], sc[kt][qt][3]);
      *(uint2*)(pw + (qt * 16 + lanelow) * P_STR + kt * 16 + quad * 4) = pk;
    }

  f32x4 oc[4][2];
  #pragma unroll
  for (int qt = 0; qt < 4; ++qt)
    #pragma unroll
    for (int dt = 0; dt < 2; ++dt) oc[qt][dt] = (f32x4){0.f, 0.f, 0.f, 0.f};
  short8 pf[4][2];
  #pragma unroll
  for (int qt = 0; qt < 4; ++qt)
    #pragma unroll
    for (int kp = 0; kp < 2; ++kp)
      pf[qt][kp] = *(const short8*)(pw + (qt * 16 + lanelow) * P_STR + kp * 32 + quad * 8);
  short8 vf[2][2];
  #pragma unroll
  for (int dt = 0; dt < 2; ++dt)
    #pragma unroll
    for (int kp = 0; kp < 2; ++kp) {
      short8 b;
      #pragma unroll
      for (int j = 0; j < 8; ++j) {
        int tok = kp * 32 + quad * 8 + j; if (tok > 48) tok = 48;
        b[j] = (short)qs[tok * QKV_STR + 256 + h * 32 + dt * 16 + lanelow];
      }
      vf[dt][kp] = b;
    }
  #pragma unroll
  for (int qt = 0; qt < 4; ++qt)
    #pragma unroll
    for (int dt = 0; dt < 2; ++dt)
      #pragma unroll
      for (int kp = 0; kp < 2; ++kp)
        oc[qt][dt] = __builtin_amdgcn_mfma_f32_16x16x32_bf16(pf[qt][kp], vf[dt][kp], oc[qt][dt], 0, 0, 0);

  #pragma unroll
  for (int qt = 0; qt < 4; ++qt)
    #pragma unroll
    for (int r = 0; r < 4; ++r) {
      int q = qt * 16 + quad * 4 + r;
      if (q < 49) {
        uint16_t* dst = aw + (size_t)(base + q) * 128 + h * 32 + lanelow;
        dst[0]  = bf16of(oc[qt][0][r]);
        dst[16] = bf16of(oc[qt][1][r]);
      }
    }
}

extern "C" void kernel_launch(void* const* d_in, const int* in_sizes, int n_in,
                              void* d_out, int out_size, void* d_ws, size_t ws_size,
                              hipStream_t stream) {
  const float* x0    = (const float*)d_in[0];
  const float* ln1g  = (const float*)d_in[1];
  const float* ln1b  = (const float*)d_in[2];
  const float* wqkv1 = (const float*)d_in[3];
  const float* bqkv1 = (const float*)d_in[4];
  const float* wo1   = (const float*)d_in[5];
  const float* bo1   = (const float*)d_in[6];
  const float* tbl1  = (const float*)d_in[7];
  const float* ln2g  = (const float*)d_in[8];
  const float* ln2b  = (const float*)d_in[9];
  const float* wm1   = (const float*)d_in[10];
  const float* bm1   = (const float*)d_in[11];
  const float* ln3g  = (const float*)d_in[12];
  const float* ln3b  = (const float*)d_in[13];
  const float* wqkv2 = (const float*)d_in[14];
  const float* bqkv2 = (const float*)d_in[15];
  const float* wo2   = (const float*)d_in[16];
  const float* bo2   = (const float*)d_in[17];
  const float* tbl2  = (const float*)d_in[18];
  const float* ln4g  = (const float*)d_in[19];
  const float* ln4b  = (const float*)d_in[20];
  const float* wm2   = (const float*)d_in[21];
  const float* bm2   = (const float*)d_in[22];

  char* ws = (char*)d_ws;
  size_t off = 0;
  uint16_t* qkvb = (uint16_t*)(ws + off); off += (size_t)NTOK * 384 * sizeof(uint16_t);
  uint16_t* awb  = (uint16_t*)(ws + off); off += (size_t)NTOK * 128 * sizeof(uint16_t);
  uint16_t* xb   = (uint16_t*)(ws + off); off += (size_t)NTOK * 128 * sizeof(uint16_t);
  float* biasT1  = (float*)(ws + off);    off += 16384 * sizeof(float);
  float* biasT2  = (float*)(ws + off);    off += 16384 * sizeof(float);
  uint16_t* wb   = (uint16_t*)(ws + off); off += 163840 * sizeof(uint16_t);
  if (ws_size < off) return;
  float* x1 = (float*)d_out;   // single f32 stream, in-place residual updates

  uint16_t* wqkv1b = wb;
  uint16_t* wqkv2b = wb + 49152;
  uint16_t* wo1b   = wb + 98304;
  uint16_t* wm1b   = wb + 114688;
  uint16_t* wo2b   = wb + 131072;
  uint16_t* wm2b   = wb + 147456;

  dim3 blk(256);
  dim3 lgrid(NTOK / 4);
  dim3 g3m(3, 1568);        // qkv: N=384
  dim3 g1m(1, 1568);        // proj/mlp: N=128
  dim3 agrid(4096);

  wconv_k<<<640, blk, 0, stream>>>(wqkv1, wqkv2, wo1, wm1, wo2, wm2, wb);
  bias_k<<<64, blk, 0, stream>>>(tbl1, biasT1);
  bias_k<<<64, blk, 0, stream>>>(tbl2, biasT2);

  // block 1: W-MSA
  ln_k<<<lgrid, blk, 0, stream>>>(x0, ln1g, ln1b, xb);
  gemm_m2<0, -1, false, true><<<g3m, blk, 0, stream>>>(xb, wqkv1b, bqkv1, nullptr, qkvb, 384);
  attn_m<<<agrid, blk, 0, stream>>>(qkvb, biasT1, awb);
  gemm_m2<-1, -1, true, false><<<g1m, blk, 0, stream>>>(awb, wo1b, bo1, x0, x1, 128);
  // mlp1 (in-place residual on x1)
  ln_k<<<lgrid, blk, 0, stream>>>(x1, ln2g, ln2b, xb);
  gemm_m2<-1, -1, true, false><<<g1m, blk, 0, stream>>>(xb, wm1b, bm1, x1, x1, 128);
  // block 2: SW-MSA
  ln_k<<<lgrid, blk, 0, stream>>>(x1, ln3g, ln3b, xb);
  gemm_m2<3, -1, false, true><<<g3m, blk, 0, stream>>>(xb, wqkv2b, bqkv2, nullptr, qkvb, 384);
  attn_m<<<agrid, blk, 0, stream>>>(qkvb, biasT2, awb);
  gemm_m2<-1, 3, true, false><<<g1m, blk, 0, stream>>>(awb, wo2b, bo2, x1, x1, 128);
  // mlp2 -> final output (reads only xb, overwrite of stream is safe)
  ln_k<<<lgrid, blk, 0, stream>>>(x1, ln4g, ln4b, xb);
  gemm_m2<-1, -1, false, false><<<g1m, blk, 0, stream>>>(xb, wm2b, bm2, nullptr, d_out, 128);
}

// Round 3
// 994.122 us; speedup vs baseline: 2.0721x; 1.0551x over previous
//
#include <hip/hip_runtime.h>
#include <hip/hip_bf16.h>
#include <stdint.h>

#define PS 56
#define S_ 3136
#define DIM 128
#define NTOK 200704   // 64 * 3136

typedef __attribute__((ext_vector_type(8))) short short8;
typedef __attribute__((ext_vector_type(4))) float f32x4;

__device__ __forceinline__ float bflo(uint32_t u){ return __uint_as_float(u << 16); }
__device__ __forceinline__ float bfhi(uint32_t u){ return __uint_as_float(u & 0xffff0000u); }
__device__ __forceinline__ uint32_t bfpack(float a, float b){
  uint32_t ua = __float_as_uint(a); ua = (ua + 0x7fffu + ((ua >> 16) & 1u)) >> 16;
  uint32_t ub = __float_as_uint(b); ub = (ub + 0x7fffu + ((ub >> 16) & 1u)) & 0xffff0000u;
  return ua | ub;
}
__device__ __forceinline__ uint16_t bf16of(float a){
  uint32_t ua = __float_as_uint(a);
  return (uint16_t)((ua + 0x7fffu + ((ua >> 16) & 1u)) >> 16);
}

__device__ __forceinline__ int win_map(int r, int shift) {
  int b = r / S_;
  int rem = r - b * S_;
  int w = rem / 49;
  int p = rem - w * 49;
  int i = p / 7, j = p - i * 7;
  int wr = w >> 3, wc = w & 7;
  int row = wr * 7 + i + shift; if (row >= PS) row -= PS;
  int col = wc * 7 + j + shift; if (col >= PS) col -= PS;
  return b * S_ + row * PS + col;
}

// ===== LN fused to bf16 (standalone, used once for ln1) =====
__global__ __launch_bounds__(256) void ln_k(const float* __restrict__ X,
                                            const float* __restrict__ g,
                                            const float* __restrict__ b,
                                            uint16_t* __restrict__ O) {
  int t = blockIdx.x * 4 + (threadIdx.x >> 6);
  int lane = threadIdx.x & 63;
  float2 v = *(const float2*)(X + (size_t)t * DIM + lane * 2);
  float s = v.x + v.y, sq = v.x * v.x + v.y * v.y;
  #pragma unroll
  for (int o = 32; o; o >>= 1) { s += __shfl_xor(s, o); sq += __shfl_xor(sq, o); }
  float mu = s * (1.0f / 128.0f);
  float rs = rsqrtf(sq * (1.0f / 128.0f) - mu * mu + 1e-5f);
  float2 gg = *(const float2*)(g + lane * 2);
  float2 bb = *(const float2*)(b + lane * 2);
  float a = (v.x - mu) * rs * gg.x + bb.x;
  float c = (v.y - mu) * rs * gg.y + bb.y;
  ((uint32_t*)O)[(size_t)t * 64 + lane] = bfpack(a, c);
}

// ===== one-shot weight conversion f32 -> bf16 =====
__global__ __launch_bounds__(256) void wconv_k(
    const float* __restrict__ w0, const float* __restrict__ w1,
    const float* __restrict__ w2, const float* __restrict__ w3,
    const float* __restrict__ w4, const float* __restrict__ w5,
    uint16_t* __restrict__ out) {
  int i = blockIdx.x * 256 + threadIdx.x;   // 0..163839
  float v;
  if      (i <  49152) v = w0[i];
  else if (i <  98304) v = w1[i -  49152];
  else if (i < 114688) v = w2[i -  98304];
  else if (i < 131072) v = w3[i - 114688];
  else if (i < 147456) v = w4[i - 131072];
  else                 v = w5[i - 147456];
  out[i] = bf16of(v);
}

// ================= MFMA GEMM (verified) — used for qkv (bf16 out) and mlp2 (f32 out) =================
constexpr int MKC = 64, MKSTR = MKC + 8;

template<int IN_SHIFT, int OUT_SHIFT, bool RES, bool OUT_BF16>
__global__ __launch_bounds__(256) void gemm_m2(
    const uint16_t* __restrict__ A, const uint16_t* __restrict__ Wb,
    const float* __restrict__ bias, const float* __restrict__ Rsrc,
    void* __restrict__ Out, int Ncols)
{
  __shared__ __align__(16) uint16_t As[128][MKSTR];
  __shared__ __align__(16) uint16_t Ws[128][MKSTR];
  const int tid = threadIdx.x;
  const int lane = tid & 63;
  const int lanelow = lane & 15;
  const int quad = lane >> 4;
  const int wid = tid >> 6;
  const int wave_m = wid >> 1, wave_n = wid & 1;
  const int mtile = blockIdx.y * 128;
  const int ntile = blockIdx.x * 128;

  f32x4 acc[4][4];
  #pragma unroll
  for (int mt = 0; mt < 4; ++mt)
    #pragma unroll
    for (int nt = 0; nt < 4; ++nt) acc[mt][nt] = (f32x4){0.f, 0.f, 0.f, 0.f};

  for (int kc = 0; kc < DIM; kc += MKC) {
    #pragma unroll
    for (int it = 0; it < 8; ++it) {
      int idx = tid + it * 256;
      int m = idx >> 4;
      int k4 = (idx & 15) << 2;
      int gm = mtile + m;
      int src = (IN_SHIFT < 0) ? gm : win_map(gm, IN_SHIFT);
      *(uint2*)&As[m][k4] = *(const uint2*)(A + (size_t)src * DIM + kc + k4);
    }
    #pragma unroll
    for (int it = 0; it < 8; ++it) {
      int idx = tid + it * 256;
      int n = idx >> 4;
      int k4 = (idx & 15) << 2;
      *(uint2*)&Ws[n][k4] = *(const uint2*)(Wb + (size_t)(ntile + n) * DIM + kc + k4);
    }
    __syncthreads();
    #pragma unroll
    for (int k0 = 0; k0 < MKC; k0 += 32) {
      short8 af[4], bf[4];
      #pragma unroll
      for (int mt = 0; mt < 4; ++mt)
        af[mt] = *(const short8*)&As[wave_m * 64 + mt * 16 + lanelow][k0 + quad * 8];
      #pragma unroll
      for (int nt = 0; nt < 4; ++nt)
        bf[nt] = *(const short8*)&Ws[wave_n * 64 + nt * 16 + lanelow][k0 + quad * 8];
      #pragma unroll
      for (int mt = 0; mt < 4; ++mt)
        #pragma unroll
        for (int nt = 0; nt < 4; ++nt)
          acc[mt][nt] = __builtin_amdgcn_mfma_f32_16x16x32_bf16(af[mt], bf[nt], acc[mt][nt], 0, 0, 0);
    }
    __syncthreads();
  }
  #pragma unroll
  for (int nt = 0; nt < 4; ++nt) {
    int col = ntile + wave_n * 64 + nt * 16 + lanelow;
    float bb = bias[col];
    #pragma unroll
    for (int mt = 0; mt < 4; ++mt) {
      #pragma unroll
      for (int r = 0; r < 4; ++r) {
        int gm = mtile + wave_m * 64 + mt * 16 + quad * 4 + r;
        float v = acc[mt][nt][r] + bb;
        if constexpr (OUT_BF16) {
          ((uint16_t*)Out)[(size_t)gm * Ncols + col] = bf16of(v);
        } else {
          int orow = (OUT_SHIFT < 0) ? gm : win_map(gm, OUT_SHIFT);
          if constexpr (RES) v += Rsrc[(size_t)orow * DIM + col];
          ((float*)Out)[(size_t)orow * (size_t)Ncols + col] = v;
        }
      }
    }
  }
}

// ================= gemm_m3: mlp GEMM + bias + residual + fused next-LN =================
__global__ __launch_bounds__(256) void gemm_m3(
    const uint16_t* __restrict__ A, const uint16_t* __restrict__ Wb,
    const float* __restrict__ bias, const float* __restrict__ Rsrc,
    float* __restrict__ Xout, const float* __restrict__ lng,
    const float* __restrict__ lnb, uint16_t* __restrict__ xb)
{
  __shared__ __align__(16) uint16_t As[128][MKSTR];
  __shared__ __align__(16) uint16_t Ws[128][MKSTR];
  __shared__ float lnred[128][2][2];
  const int tid = threadIdx.x;
  const int lane = tid & 63;
  const int lanelow = lane & 15;
  const int quad = lane >> 4;
  const int wid = tid >> 6;
  const int wave_m = wid >> 1, wave_n = wid & 1;
  const int mtile = blockIdx.y * 128;

  f32x4 acc[4][4];
  #pragma unroll
  for (int mt = 0; mt < 4; ++mt)
    #pragma unroll
    for (int nt = 0; nt < 4; ++nt) acc[mt][nt] = (f32x4){0.f, 0.f, 0.f, 0.f};

  for (int kc = 0; kc < DIM; kc += MKC) {
    #pragma unroll
    for (int it = 0; it < 8; ++it) {
      int idx = tid + it * 256;
      int m = idx >> 4;
      int k4 = (idx & 15) << 2;
      *(uint2*)&As[m][k4] = *(const uint2*)(A + (size_t)(mtile + m) * DIM + kc + k4);
    }
    #pragma unroll
    for (int it = 0; it < 8; ++it) {
      int idx = tid + it * 256;
      int n = idx >> 4;
      int k4 = (idx & 15) << 2;
      *(uint2*)&Ws[n][k4] = *(const uint2*)(Wb + (size_t)n * DIM + kc + k4);
    }
    __syncthreads();
    #pragma unroll
    for (int k0 = 0; k0 < MKC; k0 += 32) {
      short8 af[4], bf[4];
      #pragma unroll
      for (int mt = 0; mt < 4; ++mt)
        af[mt] = *(const short8*)&As[wave_m * 64 + mt * 16 + lanelow][k0 + quad * 8];
      #pragma unroll
      for (int nt = 0; nt < 4; ++nt)
        bf[nt] = *(const short8*)&Ws[wave_n * 64 + nt * 16 + lanelow][k0 + quad * 8];
      #pragma unroll
      for (int mt = 0; mt < 4; ++mt)
        #pragma unroll
        for (int nt = 0; nt < 4; ++nt)
          acc[mt][nt] = __builtin_amdgcn_mfma_f32_16x16x32_bf16(af[mt], bf[nt], acc[mt][nt], 0, 0, 0);
    }
    __syncthreads();
  }
  float bb[4], gg[4], bt[4];
  #pragma unroll
  for (int nt = 0; nt < 4; ++nt) {
    int col = wave_n * 64 + nt * 16 + lanelow;
    bb[nt] = bias[col]; gg[nt] = lng[col]; bt[nt] = lnb[col];
  }
  // pass 1: v = acc + bias + residual (stored back into acc), per-row partial sums
  #pragma unroll
  for (int mt = 0; mt < 4; ++mt)
    #pragma unroll
    for (int r = 0; r < 4; ++r) {
      int gm = mtile + wave_m * 64 + mt * 16 + quad * 4 + r;
      float s = 0.f, sq = 0.f;
      #pragma unroll
      for (int nt = 0; nt < 4; ++nt) {
        int col = wave_n * 64 + nt * 16 + lanelow;
        float v = acc[mt][nt][r] + bb[nt] + Rsrc[(size_t)gm * DIM + col];
        acc[mt][nt][r] = v;
        s += v; sq += v * v;
      }
      s += __shfl_xor(s, 1); sq += __shfl_xor(sq, 1);
      s += __shfl_xor(s, 2); sq += __shfl_xor(sq, 2);
      s += __shfl_xor(s, 4); sq += __shfl_xor(sq, 4);
      s += __shfl_xor(s, 8); sq += __shfl_xor(sq, 8);
      if (lanelow == 0) {
        int lr = wave_m * 64 + mt * 16 + quad * 4 + r;
        lnred[lr][wave_n][0] = s;
        lnred[lr][wave_n][1] = sq;
      }
    }
  __syncthreads();
  // pass 2: finalize LN, write f32 stream + bf16 normalized copy
  #pragma unroll
  for (int mt = 0; mt < 4; ++mt)
    #pragma unroll
    for (int r = 0; r < 4; ++r) {
      int lr = wave_m * 64 + mt * 16 + quad * 4 + r;
      int gm = mtile + lr;
      float s  = lnred[lr][0][0] + lnred[lr][1][0];
      float sq = lnred[lr][0][1] + lnred[lr][1][1];
      float mu = s * (1.0f / 128.0f);
      float rs = rsqrtf(sq * (1.0f / 128.0f) - mu * mu + 1e-5f);
      #pragma unroll
      for (int nt = 0; nt < 4; ++nt) {
        int col = wave_n * 64 + nt * 16 + lanelow;
        float v = acc[mt][nt][r];
        Xout[(size_t)gm * DIM + col] = v;
        xb[(size_t)gm * DIM + col] = bf16of((v - mu) * rs * gg[nt] + bt[nt]);
      }
    }
}

// ================= bias precompute: biasT[h][k][q], mask baked =================
__global__ __launch_bounds__(256) void bias_k(const float* __restrict__ tbl, float* __restrict__ biasT) {
  int idx = blockIdx.x * 256 + threadIdx.x;   // (h<<12 | k<<6 | q)
  int h = idx >> 12;
  int k = (idx >> 6) & 63;
  int q = idx & 63;
  float v;
  if (k >= 49)      v = -1e30f;
  else if (q >= 49) v = 0.f;
  else {
    int yi = q / 7, xi = q - yi * 7;
    int yj = k / 7, xj = k - yj * 7;
    v = tbl[((yi - yj + 6) * 13 + (xi - xj + 6)) * 4 + h];
  }
  biasT[idx] = v;
}

// ===== fused attention: QK^T+softmax+PV (verified core) + Wo proj + residual + next-LN =====
constexpr int QKV_STR = 392;
constexpr int P_STR   = 72;
constexpr int OS_STR  = 140;   // O tile stride (bf16): 70 dwords -> conflict-free frags

template<int OUT_SHIFT>
__global__ __launch_bounds__(256) void attn2(const uint16_t* __restrict__ qkv,
                                             const float* __restrict__ biasT,
                                             const uint16_t* __restrict__ Wo,
                                             const float* __restrict__ bo,
                                             const float* __restrict__ Rsrc,
                                             float* __restrict__ Xout,
                                             const float* __restrict__ lng,
                                             const float* __restrict__ lnb,
                                             uint16_t* __restrict__ xb)
{
  __shared__ __align__(16) uint16_t qs[49 * QKV_STR];
  __shared__ __align__(16) uint16_t ps[4][64 * P_STR];
  __shared__ float lnred[64][4][2];
  const int tid = threadIdx.x;
  const int lane = tid & 63;
  const int h = tid >> 6;
  const int lanelow = lane & 15;
  const int quad = lane >> 4;
  const int base = blockIdx.x * 49;

  for (int c = tid; c < 2352; c += 256) {
    int row = c / 48;
    int col = (c - row * 48) * 8;
    *(float4*)(qs + row * QKV_STR + col) =
        *(const float4*)(qkv + (size_t)(base + row) * 384 + col);
  }
  __syncthreads();

  // ---- S^T = K·Q^T ----
  f32x4 sc[4][4];
  #pragma unroll
  for (int kt = 0; kt < 4; ++kt)
    #pragma unroll
    for (int qt = 0; qt < 4; ++qt) sc[kt][qt] = (f32x4){0.f, 0.f, 0.f, 0.f};
  {
    short8 kf[4], qf[4];
    const int kcol = 128 + h * 32 + quad * 8;
    const int qcol = h * 32 + quad * 8;
    #pragma unroll
    for (int t = 0; t < 4; ++t) {
      int tok = t * 16 + lanelow; if (tok > 48) tok = 48;
      kf[t] = *(const short8*)(qs + tok * QKV_STR + kcol);
      qf[t] = *(const short8*)(qs + tok * QKV_STR + qcol);
    }
    #pragma unroll
    for (int kt = 0; kt < 4; ++kt)
      #pragma unroll
      for (int qt = 0; qt < 4; ++qt)
        sc[kt][qt] = __builtin_amdgcn_mfma_f32_16x16x32_bf16(kf[kt], qf[qt], sc[kt][qt], 0, 0, 0);
  }

  // ---- scale + bias + softmax over k ----
  const float* bh = biasT + h * 4096;
  #pragma unroll
  for (int kt = 0; kt < 4; ++kt)
    #pragma unroll
    for (int r = 0; r < 4; ++r) {
      const float* br = bh + (kt * 16 + quad * 4 + r) * 64 + lanelow;
      #pragma unroll
      for (int qt = 0; qt < 4; ++qt)
        sc[kt][qt][r] = fmaf(sc[kt][qt][r], 0.17677669529663689f, br[qt * 16]);
    }
  #pragma unroll
  for (int qt = 0; qt < 4; ++qt) {
    float m = sc[0][qt][0];
    #pragma unroll
    for (int kt = 0; kt < 4; ++kt)
      #pragma unroll
      for (int r = 0; r < 4; ++r) m = fmaxf(m, sc[kt][qt][r]);
    m = fmaxf(m, __shfl_xor(m, 16));
    m = fmaxf(m, __shfl_xor(m, 32));
    float s = 0.f;
    #pragma unroll
    for (int kt = 0; kt < 4; ++kt)
      #pragma unroll
      for (int r = 0; r < 4; ++r) {
        float e = __expf(sc[kt][qt][r] - m);
        sc[kt][qt][r] = e;
        s += e;
      }
    s += __shfl_xor(s, 16);
    s += __shfl_xor(s, 32);
    float inv = 1.0f / s;
    #pragma unroll
    for (int kt = 0; kt < 4; ++kt)
      #pragma unroll
      for (int r = 0; r < 4; ++r) sc[kt][qt][r] *= inv;
  }

  // ---- P (bf16) -> per-wave LDS transpose ----
  uint16_t* pw = &ps[h][0];
  #pragma unroll
  for (int qt = 0; qt < 4; ++qt)
    #pragma unroll
    for (int kt = 0; kt < 4; ++kt) {
      uint2 pk;
      pk.x = bfpack(sc[kt][qt][0], sc[kt][qt][1]);
      pk.y = bfpack(sc[kt][qt][2], sc[kt][qt][3]);
      *(uint2*)(pw + (qt * 16 + lanelow) * P_STR + kt * 16 + quad * 4) = pk;
    }

  // ---- O = P·V ----
  f32x4 oc[4][2];
  #pragma unroll
  for (int qt = 0; qt < 4; ++qt)
    #pragma unroll
    for (int dt = 0; dt < 2; ++dt) oc[qt][dt] = (f32x4){0.f, 0.f, 0.f, 0.f};
  {
    short8 pf[4][2];
    #pragma unroll
    for (int qt = 0; qt < 4; ++qt)
      #pragma unroll
      for (int kp = 0; kp < 2; ++kp)
        pf[qt][kp] = *(const short8*)(pw + (qt * 16 + lanelow) * P_STR + kp * 32 + quad * 8);
    short8 vf[2][2];
    #pragma unroll
    for (int dt = 0; dt < 2; ++dt)
      #pragma unroll
      for (int kp = 0; kp < 2; ++kp) {
        short8 b;
        #pragma unroll
        for (int j = 0; j < 8; ++j) {
          int tok = kp * 32 + quad * 8 + j; if (tok > 48) tok = 48;
          b[j] = (short)qs[tok * QKV_STR + 256 + h * 32 + dt * 16 + lanelow];
        }
        vf[dt][kp] = b;
      }
    #pragma unroll
    for (int qt = 0; qt < 4; ++qt)
      #pragma unroll
      for (int dt = 0; dt < 2; ++dt)
        #pragma unroll
        for (int kp = 0; kp < 2; ++kp)
          oc[qt][dt] = __builtin_amdgcn_mfma_f32_16x16x32_bf16(pf[qt][kp], vf[dt][kp], oc[qt][dt], 0, 0, 0);
  }

  // ---- O -> LDS (alias over ps; all LDS reads above are complete) ----
  __syncthreads();
  uint16_t* Os = (uint16_t*)ps;
  #pragma unroll
  for (int qt = 0; qt < 4; ++qt)
    #pragma unroll
    for (int r = 0; r < 4; ++r) {
      int t = qt * 16 + quad * 4 + r;
      #pragma unroll
      for (int dt = 0; dt < 2; ++dt)
        Os[t * OS_STR + h * 32 + dt * 16 + lanelow] = bf16of(oc[qt][dt][r]);
    }
  __syncthreads();

  // ---- proj: rc = O @ Wo^T, this wave computes cols h*32..h*32+31 ----
  f32x4 rc[4][2];
  #pragma unroll
  for (int qt = 0; qt < 4; ++qt)
    #pragma unroll
    for (int dt = 0; dt < 2; ++dt) rc[qt][dt] = (f32x4){0.f, 0.f, 0.f, 0.f};
  #pragma unroll
  for (int kp = 0; kp < 4; ++kp) {
    short8 af[4];
    #pragma unroll
    for (int qt = 0; qt < 4; ++qt)
      af[qt] = *(const short8*)&Os[(qt * 16 + lanelow) * OS_STR + kp * 32 + quad * 8];
    short8 bfr[2];
    #pragma unroll
    for (int dt = 0; dt < 2; ++dt)
      bfr[dt] = *(const short8*)(Wo + (size_t)(h * 32 + dt * 16 + lanelow) * DIM + kp * 32 + quad * 8);
    #pragma unroll
    for (int qt = 0; qt < 4; ++qt)
      #pragma unroll
      for (int dt = 0; dt < 2; ++dt)
        rc[qt][dt] = __builtin_amdgcn_mfma_f32_16x16x32_bf16(af[qt], bfr[dt], rc[qt][dt], 0, 0, 0);
  }

  // ---- bias + residual (in place), per-row LN partials ----
  const int n0 = h * 32 + lanelow, n1 = n0 + 16;
  const float b0 = bo[n0], b1 = bo[n1];
  const float g0 = lng[n0], g1 = lng[n1];
  const float e0 = lnb[n0], e1 = lnb[n1];
  #pragma unroll
  for (int qt = 0; qt < 4; ++qt)
    #pragma unroll
    for (int r = 0; r < 4; ++r) {
      int q = qt * 16 + quad * 4 + r;
      int wrow = base + q;
      int orow = (OUT_SHIFT < 0) ? wrow : win_map(wrow, OUT_SHIFT);
      bool ok = (q < 49);
      float r0 = ok ? Rsrc[(size_t)orow * DIM + n0] : 0.f;
      float r1 = ok ? Rsrc[(size_t)orow * DIM + n1] : 0.f;
      float v0 = rc[qt][0][r] + b0 + r0;
      float v1 = rc[qt][1][r] + b1 + r1;
      rc[qt][0][r] = v0; rc[qt][1][r] = v1;
      float s = v0 + v1, sq = v0 * v0 + v1 * v1;
      s += __shfl_xor(s, 1); sq += __shfl_xor(sq, 1);
      s += __shfl_xor(s, 2); sq += __shfl_xor(sq, 2);
      s += __shfl_xor(s, 4); sq += __shfl_xor(sq, 4);
      s += __shfl_xor(s, 8); sq += __shfl_xor(sq, 8);
      if (lanelow == 0) { lnred[q][h][0] = s; lnred[q][h][1] = sq; }
    }
  __syncthreads();
  // ---- finalize: write f32 stream + LN-normalized bf16 ----
  #pragma unroll
  for (int qt = 0; qt < 4; ++qt)
    #pragma unroll
    for (int r = 0; r < 4; ++r) {
      int q = qt * 16 + quad * 4 + r;
      if (q < 49) {
        int wrow = base + q;
        int orow = (OUT_SHIFT < 0) ? wrow : win_map(wrow, OUT_SHIFT);
        float s  = lnred[q][0][0] + lnred[q][1][0] + lnred[q][2][0] + lnred[q][3][0];
        float sq = lnred[q][0][1] + lnred[q][1][1] + lnred[q][2][1] + lnred[q][3][1];
        float mu = s * (1.0f / 128.0f);
        float rs = rsqrtf(sq * (1.0f / 128.0f) - mu * mu + 1e-5f);
        float v0 = rc[qt][0][r], v1 = rc[qt][1][r];
        Xout[(size_t)orow * DIM + n0] = v0;
        Xout[(size_t)orow * DIM + n1] = v1;
        xb[(size_t)orow * DIM + n0] = bf16of((v0 - mu) * rs * g0 + e0);
        xb[(size_t)orow * DIM + n1] = bf16of((v1 - mu) * rs * g1 + e1);
      }
    }
}

extern "C" void kernel_launch(void* const* d_in, const int* in_sizes, int n_in,
                              void* d_out, int out_size, void* d_ws, size_t ws_size,
                              hipStream_t stream) {
  const float* x0    = (const float*)d_in[0];
  const float* ln1g  = (const float*)d_in[1];
  const float* ln1b  = (const float*)d_in[2];
  const float* wqkv1 = (const float*)d_in[3];
  const float* bqkv1 = (const float*)d_in[4];
  const float* wo1   = (const float*)d_in[5];
  const float* bo1   = (const float*)d_in[6];
  const float* tbl1  = (const float*)d_in[7];
  const float* ln2g  = (const float*)d_in[8];
  const float* ln2b  = (const float*)d_in[9];
  const float* wm1   = (const float*)d_in[10];
  const float* bm1   = (const float*)d_in[11];
  const float* ln3g  = (const float*)d_in[12];
  const float* ln3b  = (const float*)d_in[13];
  const float* wqkv2 = (const float*)d_in[14];
  const float* bqkv2 = (const float*)d_in[15];
  const float* wo2   = (const float*)d_in[16];
  const float* bo2   = (const float*)d_in[17];
  const float* tbl2  = (const float*)d_in[18];
  const float* ln4g  = (const float*)d_in[19];
  const float* ln4b  = (const float*)d_in[20];
  const float* wm2   = (const float*)d_in[21];
  const float* bm2   = (const float*)d_in[22];

  char* ws = (char*)d_ws;
  size_t off = 0;
  uint16_t* qkvb = (uint16_t*)(ws + off); off += (size_t)NTOK * 384 * sizeof(uint16_t);
  uint16_t* xb   = (uint16_t*)(ws + off); off += (size_t)NTOK * 128 * sizeof(uint16_t);
  float* biasT1  = (float*)(ws + off);    off += 16384 * sizeof(float);
  float* biasT2  = (float*)(ws + off);    off += 16384 * sizeof(float);
  uint16_t* wb   = (uint16_t*)(ws + off); off += 163840 * sizeof(uint16_t);
  if (ws_size < off) return;
  float* x1 = (float*)d_out;   // single f32 stream, in-place residual updates

  uint16_t* wqkv1b = wb;
  uint16_t* wqkv2b = wb + 49152;
  uint16_t* wo1b   = wb + 98304;
  uint16_t* wm1b   = wb + 114688;
  uint16_t* wo2b   = wb + 131072;
  uint16_t* wm2b   = wb + 147456;

  dim3 blk(256);
  dim3 lgrid(NTOK / 4);
  dim3 g3m(3, 1568);        // qkv: N=384
  dim3 g1m(1, 1568);        // mlp: N=128
  dim3 agrid(4096);

  wconv_k<<<640, blk, 0, stream>>>(wqkv1, wqkv2, wo1, wm1, wo2, wm2, wb);
  bias_k<<<64, blk, 0, stream>>>(tbl1, biasT1);
  bias_k<<<64, blk, 0, stream>>>(tbl2, biasT2);

  // block 1: W-MSA  (faithful quirk: proj1 output rows are identity, no inverse window map)
  ln_k<<<lgrid, blk, 0, stream>>>(x0, ln1g, ln1b, xb);
  gemm_m2<0, -1, false, true><<<g3m, blk, 0, stream>>>(xb, wqkv1b, bqkv1, nullptr, qkvb, 384);
  attn2<-1><<<agrid, blk, 0, stream>>>(qkvb, biasT1, wo1b, bo1, x0, x1, ln2g, ln2b, xb);
  // mlp1 + fused ln3
  gemm_m3<<<g1m, blk, 0, stream>>>(xb, wm1b, bm1, x1, x1, ln3g, ln3b, xb);
  // block 2: SW-MSA (output rows via inverse window + roll(+3))
  gemm_m2<3, -1, false, true><<<g3m, blk, 0, stream>>>(xb, wqkv2b, bqkv2, nullptr, qkvb, 384);
  attn2<3><<<agrid, blk, 0, stream>>>(qkvb, biasT2, wo2b, bo2, x1, x1, ln4g, ln4b, xb);
  // mlp2 -> final output (reads only xb; overwriting the stream is safe)
  gemm_m2<-1, -1, false, false><<<g1m, blk, 0, stream>>>(xb, wm2b, bm2, nullptr, d_out, 128);
}

// Round 4
// 927.839 us; speedup vs baseline: 2.2201x; 1.0714x over previous
//
#include <hip/hip_runtime.h>
#include <hip/hip_bf16.h>
#include <stdint.h>

#define PS 56
#define S_ 3136
#define DIM 128
#define NTOK 200704   // 64 * 3136

typedef __attribute__((ext_vector_type(8))) short short8;
typedef __attribute__((ext_vector_type(4))) float f32x4;

__device__ __forceinline__ float bflo(uint32_t u){ return __uint_as_float(u << 16); }
__device__ __forceinline__ float bfhi(uint32_t u){ return __uint_as_float(u & 0xffff0000u); }
__device__ __forceinline__ uint32_t bfpack(float a, float b){
  uint32_t ua = __float_as_uint(a); ua = (ua + 0x7fffu + ((ua >> 16) & 1u)) >> 16;
  uint32_t ub = __float_as_uint(b); ub = (ub + 0x7fffu + ((ub >> 16) & 1u)) & 0xffff0000u;
  return ua | ub;
}
__device__ __forceinline__ uint16_t bf16of(float a){
  uint32_t ua = __float_as_uint(a);
  return (uint16_t)((ua + 0x7fffu + ((ua >> 16) & 1u)) >> 16);
}

__device__ __forceinline__ int win_map(int r, int shift) {
  int b = r / S_;
  int rem = r - b * S_;
  int w = rem / 49;
  int p = rem - w * 49;
  int i = p / 7, j = p - i * 7;
  int wr = w >> 3, wc = w & 7;
  int row = wr * 7 + i + shift; if (row >= PS) row -= PS;
  int col = wc * 7 + j + shift; if (col >= PS) col -= PS;
  return b * S_ + row * PS + col;
}

// ===== LN fused to bf16 (standalone, used once for ln1) =====
__global__ __launch_bounds__(256) void ln_k(const float* __restrict__ X,
                                            const float* __restrict__ g,
                                            const float* __restrict__ b,
                                            uint16_t* __restrict__ O) {
  int t = blockIdx.x * 4 + (threadIdx.x >> 6);
  int lane = threadIdx.x & 63;
  float2 v = *(const float2*)(X + (size_t)t * DIM + lane * 2);
  float s = v.x + v.y, sq = v.x * v.x + v.y * v.y;
  #pragma unroll
  for (int o = 32; o; o >>= 1) { s += __shfl_xor(s, o); sq += __shfl_xor(sq, o); }
  float mu = s * (1.0f / 128.0f);
  float rs = rsqrtf(sq * (1.0f / 128.0f) - mu * mu + 1e-5f);
  float2 gg = *(const float2*)(g + lane * 2);
  float2 bb = *(const float2*)(b + lane * 2);
  float a = (v.x - mu) * rs * gg.x + bb.x;
  float c = (v.y - mu) * rs * gg.y + bb.y;
  ((uint32_t*)O)[(size_t)t * 64 + lane] = bfpack(a, c);
}

// ===== one-shot weight conversion f32 -> bf16 =====
__global__ __launch_bounds__(256) void wconv_k(
    const float* __restrict__ w0, const float* __restrict__ w1,
    const float* __restrict__ w2, const float* __restrict__ w3,
    const float* __restrict__ w4, const float* __restrict__ w5,
    uint16_t* __restrict__ out) {
  int i = blockIdx.x * 256 + threadIdx.x;   // 0..163839
  float v;
  if      (i <  49152) v = w0[i];
  else if (i <  98304) v = w1[i -  49152];
  else if (i < 114688) v = w2[i -  98304];
  else if (i < 131072) v = w3[i - 114688];
  else if (i < 147456) v = w4[i - 131072];
  else                 v = w5[i - 147456];
  out[i] = bf16of(v);
}

// ================= MFMA GEMM (verified) — used for qkv (bf16 out) and mlp2 (f32 out) =================
constexpr int MKC = 64, MKSTR = MKC + 8;

template<int IN_SHIFT, int OUT_SHIFT, bool RES, bool OUT_BF16>
__global__ __launch_bounds__(256) void gemm_m2(
    const uint16_t* __restrict__ A, const uint16_t* __restrict__ Wb,
    const float* __restrict__ bias, const float* __restrict__ Rsrc,
    void* __restrict__ Out, int Ncols)
{
  __shared__ __align__(16) uint16_t As[128][MKSTR];
  __shared__ __align__(16) uint16_t Ws[128][MKSTR];
  const int tid = threadIdx.x;
  const int lane = tid & 63;
  const int lanelow = lane & 15;
  const int quad = lane >> 4;
  const int wid = tid >> 6;
  const int wave_m = wid >> 1, wave_n = wid & 1;
  const int mtile = blockIdx.y * 128;
  const int ntile = blockIdx.x * 128;

  f32x4 acc[4][4];
  #pragma unroll
  for (int mt = 0; mt < 4; ++mt)
    #pragma unroll
    for (int nt = 0; nt < 4; ++nt) acc[mt][nt] = (f32x4){0.f, 0.f, 0.f, 0.f};

  for (int kc = 0; kc < DIM; kc += MKC) {
    #pragma unroll
    for (int it = 0; it < 8; ++it) {
      int idx = tid + it * 256;
      int m = idx >> 4;
      int k4 = (idx & 15) << 2;
      int gm = mtile + m;
      int src = (IN_SHIFT < 0) ? gm : win_map(gm, IN_SHIFT);
      *(uint2*)&As[m][k4] = *(const uint2*)(A + (size_t)src * DIM + kc + k4);
    }
    #pragma unroll
    for (int it = 0; it < 8; ++it) {
      int idx = tid + it * 256;
      int n = idx >> 4;
      int k4 = (idx & 15) << 2;
      *(uint2*)&Ws[n][k4] = *(const uint2*)(Wb + (size_t)(ntile + n) * DIM + kc + k4);
    }
    __syncthreads();
    #pragma unroll
    for (int k0 = 0; k0 < MKC; k0 += 32) {
      short8 af[4], bf[4];
      #pragma unroll
      for (int mt = 0; mt < 4; ++mt)
        af[mt] = *(const short8*)&As[wave_m * 64 + mt * 16 + lanelow][k0 + quad * 8];
      #pragma unroll
      for (int nt = 0; nt < 4; ++nt)
        bf[nt] = *(const short8*)&Ws[wave_n * 64 + nt * 16 + lanelow][k0 + quad * 8];
      #pragma unroll
      for (int mt = 0; mt < 4; ++mt)
        #pragma unroll
        for (int nt = 0; nt < 4; ++nt)
          acc[mt][nt] = __builtin_amdgcn_mfma_f32_16x16x32_bf16(af[mt], bf[nt], acc[mt][nt], 0, 0, 0);
    }
    __syncthreads();
  }
  #pragma unroll
  for (int nt = 0; nt < 4; ++nt) {
    int col = ntile + wave_n * 64 + nt * 16 + lanelow;
    float bb = bias[col];
    #pragma unroll
    for (int mt = 0; mt < 4; ++mt) {
      #pragma unroll
      for (int r = 0; r < 4; ++r) {
        int gm = mtile + wave_m * 64 + mt * 16 + quad * 4 + r;
        float v = acc[mt][nt][r] + bb;
        if constexpr (OUT_BF16) {
          ((uint16_t*)Out)[(size_t)gm * Ncols + col] = bf16of(v);
        } else {
          int orow = (OUT_SHIFT < 0) ? gm : win_map(gm, OUT_SHIFT);
          if constexpr (RES) v += Rsrc[(size_t)orow * DIM + col];
          ((float*)Out)[(size_t)orow * (size_t)Ncols + col] = v;
        }
      }
    }
  }
}

// ================= gemm_m3: mlp GEMM + bias + residual + fused next-LN =================
__global__ __launch_bounds__(256) void gemm_m3(
    const uint16_t* __restrict__ A, const uint16_t* __restrict__ Wb,
    const float* __restrict__ bias, const float* __restrict__ Rsrc,
    float* __restrict__ Xout, const float* __restrict__ lng,
    const float* __restrict__ lnb, uint16_t* __restrict__ xb)
{
  __shared__ __align__(16) uint16_t As[128][MKSTR];
  __shared__ __align__(16) uint16_t Ws[128][MKSTR];
  __shared__ float lnred[128][2][2];
  const int tid = threadIdx.x;
  const int lane = tid & 63;
  const int lanelow = lane & 15;
  const int quad = lane >> 4;
  const int wid = tid >> 6;
  const int wave_m = wid >> 1, wave_n = wid & 1;
  const int mtile = blockIdx.y * 128;

  f32x4 acc[4][4];
  #pragma unroll
  for (int mt = 0; mt < 4; ++mt)
    #pragma unroll
    for (int nt = 0; nt < 4; ++nt) acc[mt][nt] = (f32x4){0.f, 0.f, 0.f, 0.f};

  for (int kc = 0; kc < DIM; kc += MKC) {
    #pragma unroll
    for (int it = 0; it < 8; ++it) {
      int idx = tid + it * 256;
      int m = idx >> 4;
      int k4 = (idx & 15) << 2;
      *(uint2*)&As[m][k4] = *(const uint2*)(A + (size_t)(mtile + m) * DIM + kc + k4);
    }
    #pragma unroll
    for (int it = 0; it < 8; ++it) {
      int idx = tid + it * 256;
      int n = idx >> 4;
      int k4 = (idx & 15) << 2;
      *(uint2*)&Ws[n][k4] = *(const uint2*)(Wb + (size_t)n * DIM + kc + k4);
    }
    __syncthreads();
    #pragma unroll
    for (int k0 = 0; k0 < MKC; k0 += 32) {
      short8 af[4], bf[4];
      #pragma unroll
      for (int mt = 0; mt < 4; ++mt)
        af[mt] = *(const short8*)&As[wave_m * 64 + mt * 16 + lanelow][k0 + quad * 8];
      #pragma unroll
      for (int nt = 0; nt < 4; ++nt)
        bf[nt] = *(const short8*)&Ws[wave_n * 64 + nt * 16 + lanelow][k0 + quad * 8];
      #pragma unroll
      for (int mt = 0; mt < 4; ++mt)
        #pragma unroll
        for (int nt = 0; nt < 4; ++nt)
          acc[mt][nt] = __builtin_amdgcn_mfma_f32_16x16x32_bf16(af[mt], bf[nt], acc[mt][nt], 0, 0, 0);
    }
    __syncthreads();
  }
  float bb[4], gg[4], bt[4];
  #pragma unroll
  for (int nt = 0; nt < 4; ++nt) {
    int col = wave_n * 64 + nt * 16 + lanelow;
    bb[nt] = bias[col]; gg[nt] = lng[col]; bt[nt] = lnb[col];
  }
  #pragma unroll
  for (int mt = 0; mt < 4; ++mt)
    #pragma unroll
    for (int r = 0; r < 4; ++r) {
      int gm = mtile + wave_m * 64 + mt * 16 + quad * 4 + r;
      float s = 0.f, sq = 0.f;
      #pragma unroll
      for (int nt = 0; nt < 4; ++nt) {
        int col = wave_n * 64 + nt * 16 + lanelow;
        float v = acc[mt][nt][r] + bb[nt] + Rsrc[(size_t)gm * DIM + col];
        acc[mt][nt][r] = v;
        s += v; sq += v * v;
      }
      s += __shfl_xor(s, 1); sq += __shfl_xor(sq, 1);
      s += __shfl_xor(s, 2); sq += __shfl_xor(sq, 2);
      s += __shfl_xor(s, 4); sq += __shfl_xor(sq, 4);
      s += __shfl_xor(s, 8); sq += __shfl_xor(sq, 8);
      if (lanelow == 0) {
        int lr = wave_m * 64 + mt * 16 + quad * 4 + r;
        lnred[lr][wave_n][0] = s;
        lnred[lr][wave_n][1] = sq;
      }
    }
  __syncthreads();
  #pragma unroll
  for (int mt = 0; mt < 4; ++mt)
    #pragma unroll
    for (int r = 0; r < 4; ++r) {
      int lr = wave_m * 64 + mt * 16 + quad * 4 + r;
      int gm = mtile + lr;
      float s  = lnred[lr][0][0] + lnred[lr][1][0];
      float sq = lnred[lr][0][1] + lnred[lr][1][1];
      float mu = s * (1.0f / 128.0f);
      float rs = rsqrtf(sq * (1.0f / 128.0f) - mu * mu + 1e-5f);
      #pragma unroll
      for (int nt = 0; nt < 4; ++nt) {
        int col = wave_n * 64 + nt * 16 + lanelow;
        float v = acc[mt][nt][r];
        Xout[(size_t)gm * DIM + col] = v;
        xb[(size_t)gm * DIM + col] = bf16of((v - mu) * rs * gg[nt] + bt[nt]);
      }
    }
}

// ================= bias precompute: biasT[h][k][q], mask baked =================
__global__ __launch_bounds__(256) void bias_k(const float* __restrict__ tbl, float* __restrict__ biasT) {
  int idx = blockIdx.x * 256 + threadIdx.x;   // (h<<12 | k<<6 | q)
  int h = idx >> 12;
  int k = (idx >> 6) & 63;
  int q = idx & 63;
  float v;
  if (k >= 49)      v = -1e30f;
  else if (q >= 49) v = 0.f;
  else {
    int yi = q / 7, xi = q - yi * 7;
    int yj = k / 7, xj = k - yj * 7;
    v = tbl[((yi - yj + 6) * 13 + (xi - xj + 6)) * 4 + h];
  }
  biasT[idx] = v;
}

// ===== fused attention: QK^T+softmax+PV + Wo proj + residual + next-LN =====
// LDS diet: P stored in dead Q/K columns of qs (rows extended to 64); Os aliases qs flat.
// 52.2 KB LDS -> 3 blocks/CU (was 77.8 KB -> 2).
constexpr int QKV_STR = 392;
constexpr int OS_STR  = 140;   // O tile stride (bf16): 70 dwords -> conflict-free frags

template<int OUT_SHIFT>
__global__ __launch_bounds__(256) void attn2(const uint16_t* __restrict__ qkv,
                                             const float* __restrict__ biasT,
                                             const uint16_t* __restrict__ Wo,
                                             const float* __restrict__ bo,
                                             const float* __restrict__ Rsrc,
                                             float* __restrict__ Xout,
                                             const float* __restrict__ lng,
                                             const float* __restrict__ lnb,
                                             uint16_t* __restrict__ xb)
{
  __shared__ __align__(16) uint16_t qs[64 * QKV_STR];   // rows 0..48 staged; rows 49..63 P-pad scratch
  __shared__ float lnred[64][4][2];
  const int tid = threadIdx.x;
  const int lane = tid & 63;
  const int h = tid >> 6;
  const int lanelow = lane & 15;
  const int quad = lane >> 4;
  const int base = blockIdx.x * 49;

  for (int c = tid; c < 2352; c += 256) {
    int row = c / 48;
    int col = (c - row * 48) * 8;
    *(float4*)(qs + row * QKV_STR + col) =
        *(const float4*)(qkv + (size_t)(base + row) * 384 + col);
  }
  __syncthreads();

  // ---- S^T = K·Q^T ----
  f32x4 sc[4][4];
  #pragma unroll
  for (int kt = 0; kt < 4; ++kt)
    #pragma unroll
    for (int qt = 0; qt < 4; ++qt) sc[kt][qt] = (f32x4){0.f, 0.f, 0.f, 0.f};
  {
    short8 kf[4], qf[4];
    const int kcol = 128 + h * 32 + quad * 8;
    const int qcol = h * 32 + quad * 8;
    #pragma unroll
    for (int t = 0; t < 4; ++t) {
      int tok = t * 16 + lanelow; if (tok > 48) tok = 48;
      kf[t] = *(const short8*)(qs + tok * QKV_STR + kcol);
      qf[t] = *(const short8*)(qs + tok * QKV_STR + qcol);
    }
    // all waves hold Q,K in regs; Q/K columns of qs are now dead -> reusable for P
    __syncthreads();
    #pragma unroll
    for (int kt = 0; kt < 4; ++kt)
      #pragma unroll
      for (int qt = 0; qt < 4; ++qt)
        sc[kt][qt] = __builtin_amdgcn_mfma_f32_16x16x32_bf16(kf[kt], qf[qt], sc[kt][qt], 0, 0, 0);
  }

  // ---- scale + bias + softmax over k ----
  const float* bh = biasT + h * 4096;
  #pragma unroll
  for (int kt = 0; kt < 4; ++kt)
    #pragma unroll
    for (int r = 0; r < 4; ++r) {
      const float* br = bh + (kt * 16 + quad * 4 + r) * 64 + lanelow;
      #pragma unroll
      for (int qt = 0; qt < 4; ++qt)
        sc[kt][qt][r] = fmaf(sc[kt][qt][r], 0.17677669529663689f, br[qt * 16]);
    }
  #pragma unroll
  for (int qt = 0; qt < 4; ++qt) {
    float m = sc[0][qt][0];
    #pragma unroll
    for (int kt = 0; kt < 4; ++kt)
      #pragma unroll
      for (int r = 0; r < 4; ++r) m = fmaxf(m, sc[kt][qt][r]);
    m = fmaxf(m, __shfl_xor(m, 16));
    m = fmaxf(m, __shfl_xor(m, 32));
    float s = 0.f;
    #pragma unroll
    for (int kt = 0; kt < 4; ++kt)
      #pragma unroll
      for (int r = 0; r < 4; ++r) {
        float e = __expf(sc[kt][qt][r] - m);
        sc[kt][qt][r] = e;
        s += e;
      }
    s += __shfl_xor(s, 16);
    s += __shfl_xor(s, 32);
    float inv = 1.0f / s;
    #pragma unroll
    for (int kt = 0; kt < 4; ++kt)
      #pragma unroll
      for (int r = 0; r < 4; ++r) sc[kt][qt][r] *= inv;
  }

  // ---- P (bf16) -> transposed into dead Q/K cols: P[q][k] at qs[q*STR + h*64 + k] ----
  // wave h exclusively owns cols [h*64, h*64+64); V cols (256..384) untouched.
  uint16_t* pw = qs + h * 64;
  #pragma unroll
  for (int qt = 0; qt < 4; ++qt)
    #pragma unroll
    for (int kt = 0; kt < 4; ++kt) {
      uint2 pk;
      pk.x = bfpack(sc[kt][qt][0], sc[kt][qt][1]);
      pk.y = bfpack(sc[kt][qt][2], sc[kt][qt][3]);
      *(uint2*)(pw + (qt * 16 + lanelow) * QKV_STR + kt * 16 + quad * 4) = pk;
    }

  // ---- O = P·V ----
  f32x4 oc[4][2];
  #pragma unroll
  for (int qt = 0; qt < 4; ++qt)
    #pragma unroll
    for (int dt = 0; dt < 2; ++dt) oc[qt][dt] = (f32x4){0.f, 0.f, 0.f, 0.f};
  {
    short8 pf[4][2];
    #pragma unroll
    for (int qt = 0; qt < 4; ++qt)
      #pragma unroll
      for (int kp = 0; kp < 2; ++kp)
        pf[qt][kp] = *(const short8*)(pw + (qt * 16 + lanelow) * QKV_STR + kp * 32 + quad * 8);
    short8 vf[2][2];
    #pragma unroll
    for (int dt = 0; dt < 2; ++dt)
      #pragma unroll
      for (int kp = 0; kp < 2; ++kp) {
        short8 b;
        #pragma unroll
        for (int j = 0; j < 8; ++j) {
          int tok = kp * 32 + quad * 8 + j; if (tok > 48) tok = 48;
          b[j] = (short)qs[tok * QKV_STR + 256 + h * 32 + dt * 16 + lanelow];
        }
        vf[dt][kp] = b;
      }
    #pragma unroll
    for (int qt = 0; qt < 4; ++qt)
      #pragma unroll
      for (int dt = 0; dt < 2; ++dt)
        #pragma unroll
        for (int kp = 0; kp < 2; ++kp)
          oc[qt][dt] = __builtin_amdgcn_mfma_f32_16x16x32_bf16(pf[qt][kp], vf[dt][kp], oc[qt][dt], 0, 0, 0);
  }

  // ---- O -> LDS (alias flat over qs; all qs reads complete) ----
  __syncthreads();
  uint16_t* Os = qs;
  #pragma unroll
  for (int qt = 0; qt < 4; ++qt)
    #pragma unroll
    for (int r = 0; r < 4; ++r) {
      int t = qt * 16 + quad * 4 + r;
      #pragma unroll
      for (int dt = 0; dt < 2; ++dt)
        Os[t * OS_STR + h * 32 + dt * 16 + lanelow] = bf16of(oc[qt][dt][r]);
    }
  __syncthreads();

  // ---- proj: rc = O @ Wo^T, this wave computes cols h*32..h*32+31 ----
  f32x4 rc[4][2];
  #pragma unroll
  for (int qt = 0; qt < 4; ++qt)
    #pragma unroll
    for (int dt = 0; dt < 2; ++dt) rc[qt][dt] = (f32x4){0.f, 0.f, 0.f, 0.f};
  #pragma unroll
  for (int kp = 0; kp < 4; ++kp) {
    short8 af[4];
    #pragma unroll
    for (int qt = 0; qt < 4; ++qt)
      af[qt] = *(const short8*)&Os[(qt * 16 + lanelow) * OS_STR + kp * 32 + quad * 8];
    short8 bfr[2];
    #pragma unroll
    for (int dt = 0; dt < 2; ++dt)
      bfr[dt] = *(const short8*)(Wo + (size_t)(h * 32 + dt * 16 + lanelow) * DIM + kp * 32 + quad * 8);
    #pragma unroll
    for (int qt = 0; qt < 4; ++qt)
      #pragma unroll
      for (int dt = 0; dt < 2; ++dt)
        rc[qt][dt] = __builtin_amdgcn_mfma_f32_16x16x32_bf16(af[qt], bfr[dt], rc[qt][dt], 0, 0, 0);
  }

  // ---- bias + residual (in place), per-row LN partials ----
  const int n0 = h * 32 + lanelow, n1 = n0 + 16;
  const float b0 = bo[n0], b1 = bo[n1];
  const float g0 = lng[n0], g1 = lng[n1];
  const float e0 = lnb[n0], e1 = lnb[n1];
  #pragma unroll
  for (int qt = 0; qt < 4; ++qt)
    #pragma unroll
    for (int r = 0; r < 4; ++r) {
      int q = qt * 16 + quad * 4 + r;
      int wrow = base + q;
      int orow = (OUT_SHIFT < 0) ? wrow : win_map(wrow, OUT_SHIFT);
      bool ok = (q < 49);
      float r0 = ok ? Rsrc[(size_t)orow * DIM + n0] : 0.f;
      float r1 = ok ? Rsrc[(size_t)orow * DIM + n1] : 0.f;
      float v0 = rc[qt][0][r] + b0 + r0;
      float v1 = rc[qt][1][r] + b1 + r1;
      rc[qt][0][r] = v0; rc[qt][1][r] = v1;
      float s = v0 + v1, sq = v0 * v0 + v1 * v1;
      s += __shfl_xor(s, 1); sq += __shfl_xor(sq, 1);
      s += __shfl_xor(s, 2); sq += __shfl_xor(sq, 2);
      s += __shfl_xor(s, 4); sq += __shfl_xor(sq, 4);
      s += __shfl_xor(s, 8); sq += __shfl_xor(sq, 8);
      if (lanelow == 0) { lnred[q][h][0] = s; lnred[q][h][1] = sq; }
    }
  __syncthreads();
  // ---- finalize: write f32 stream + LN-normalized bf16 ----
  #pragma unroll
  for (int qt = 0; qt < 4; ++qt)
    #pragma unroll
    for (int r = 0; r < 4; ++r) {
      int q = qt * 16 + quad * 4 + r;
      if (q < 49) {
        int wrow = base + q;
        int orow = (OUT_SHIFT < 0) ? wrow : win_map(wrow, OUT_SHIFT);
        float s  = lnred[q][0][0] + lnred[q][1][0] + lnred[q][2][0] + lnred[q][3][0];
        float sq = lnred[q][0][1] + lnred[q][1][1] + lnred[q][2][1] + lnred[q][3][1];
        float mu = s * (1.0f / 128.0f);
        float rs = rsqrtf(sq * (1.0f / 128.0f) - mu * mu + 1e-5f);
        float v0 = rc[qt][0][r], v1 = rc[qt][1][r];
        Xout[(size_t)orow * DIM + n0] = v0;
        Xout[(size_t)orow * DIM + n1] = v1;
        xb[(size_t)orow * DIM + n0] = bf16of((v0 - mu) * rs * g0 + e0);
        xb[(size_t)orow * DIM + n1] = bf16of((v1 - mu) * rs * g1 + e1);
      }
    }
}

extern "C" void kernel_launch(void* const* d_in, const int* in_sizes, int n_in,
                              void* d_out, int out_size, void* d_ws, size_t ws_size,
                              hipStream_t stream) {
  const float* x0    = (const float*)d_in[0];
  const float* ln1g  = (const float*)d_in[1];
  const float* ln1b  = (const float*)d_in[2];
  const float* wqkv1 = (const float*)d_in[3];
  const float* bqkv1 = (const float*)d_in[4];
  const float* wo1   = (const float*)d_in[5];
  const float* bo1   = (const float*)d_in[6];
  const float* tbl1  = (const float*)d_in[7];
  const float* ln2g  = (const float*)d_in[8];
  const float* ln2b  = (const float*)d_in[9];
  const float* wm1   = (const float*)d_in[10];
  const float* bm1   = (const float*)d_in[11];
  const float* ln3g  = (const float*)d_in[12];
  const float* ln3b  = (const float*)d_in[13];
  const float* wqkv2 = (const float*)d_in[14];
  const float* bqkv2 = (const float*)d_in[15];
  const float* wo2   = (const float*)d_in[16];
  const float* bo2   = (const float*)d_in[17];
  const float* tbl2  = (const float*)d_in[18];
  const float* ln4g  = (const float*)d_in[19];
  const float* ln4b  = (const float*)d_in[20];
  const float* wm2   = (const float*)d_in[21];
  const float* bm2   = (const float*)d_in[22];

  char* ws = (char*)d_ws;
  size_t off = 0;
  uint16_t* qkvb = (uint16_t*)(ws + off); off += (size_t)NTOK * 384 * sizeof(uint16_t);
  uint16_t* xb   = (uint16_t*)(ws + off); off += (size_t)NTOK * 128 * sizeof(uint16_t);
  float* biasT1  = (float*)(ws + off);    off += 16384 * sizeof(float);
  float* biasT2  = (float*)(ws + off);    off += 16384 * sizeof(float);
  uint16_t* wb   = (uint16_t*)(ws + off); off += 163840 * sizeof(uint16_t);
  if (ws_size < off) return;
  float* x1 = (float*)d_out;   // single f32 stream, in-place residual updates

  uint16_t* wqkv1b = wb;
  uint16_t* wqkv2b = wb + 49152;
  uint16_t* wo1b   = wb + 98304;
  uint16_t* wm1b   = wb + 114688;
  uint16_t* wo2b   = wb + 131072;
  uint16_t* wm2b   = wb + 147456;

  dim3 blk(256);
  dim3 lgrid(NTOK / 4);
  dim3 g3m(3, 1568);        // qkv: N=384
  dim3 g1m(1, 1568);        // mlp: N=128
  dim3 agrid(4096);

  wconv_k<<<640, blk, 0, stream>>>(wqkv1, wqkv2, wo1, wm1, wo2, wm2, wb);
  bias_k<<<64, blk, 0, stream>>>(tbl1, biasT1);
  bias_k<<<64, blk, 0, stream>>>(tbl2, biasT2);

  // block 1: W-MSA  (faithful quirk: proj1 output rows are identity, no inverse window map)
  ln_k<<<lgrid, blk, 0, stream>>>(x0, ln1g, ln1b, xb);
  gemm_m2<0, -1, false, true><<<g3m, blk, 0, stream>>>(xb, wqkv1b, bqkv1, nullptr, qkvb, 384);
  attn2<-1><<<agrid, blk, 0, stream>>>(qkvb, biasT1, wo1b, bo1, x0, x1, ln2g, ln2b, xb);
  // mlp1 + fused ln3
  gemm_m3<<<g1m, blk, 0, stream>>>(xb, wm1b, bm1, x1, x1, ln3g, ln3b, xb);
  // block 2: SW-MSA (output rows via inverse window + roll(+3))
  gemm_m2<3, -1, false, true><<<g3m, blk, 0, stream>>>(xb, wqkv2b, bqkv2, nullptr, qkvb, 384);
  attn2<3><<<agrid, blk, 0, stream>>>(qkvb, biasT2, wo2b, bo2, x1, x1, ln4g, ln4b, xb);
  // mlp2 -> final output (reads only xb; overwriting the stream is safe)
  gemm_m2<-1, -1, false, false><<<g1m, blk, 0, stream>>>(xb, wm2b, bm2, nullptr, d_out, 128);
}

// Round 5
// 710.960 us; speedup vs baseline: 2.8973x; 1.3051x over previous
//
#include <hip/hip_runtime.h>
#include <hip/hip_bf16.h>
#include <stdint.h>

#define PS 56
#define S_ 3136
#define DIM 128
#define NTOK 200704   // 64 * 3136

typedef __attribute__((ext_vector_type(8))) short short8;
typedef __attribute__((ext_vector_type(4))) float f32x4;

__device__ __forceinline__ float bflo(uint32_t u){ return __uint_as_float(u << 16); }
__device__ __forceinline__ float bfhi(uint32_t u){ return __uint_as_float(u & 0xffff0000u); }
__device__ __forceinline__ uint32_t bfpack(float a, float b){
  uint32_t ua = __float_as_uint(a); ua = (ua + 0x7fffu + ((ua >> 16) & 1u)) >> 16;
  uint32_t ub = __float_as_uint(b); ub = (ub + 0x7fffu + ((ub >> 16) & 1u)) & 0xffff0000u;
  return ua | ub;
}
__device__ __forceinline__ uint16_t bf16of(float a){
  uint32_t ua = __float_as_uint(a);
  return (uint16_t)((ua + 0x7fffu + ((ua >> 16) & 1u)) >> 16);
}

__device__ __forceinline__ int win_map(int r, int shift) {
  int b = r / S_;
  int rem = r - b * S_;
  int w = rem / 49;
  int p = rem - w * 49;
  int i = p / 7, j = p - i * 7;
  int wr = w >> 3, wc = w & 7;
  int row = wr * 7 + i + shift; if (row >= PS) row -= PS;
  int col = wc * 7 + j + shift; if (col >= PS) col -= PS;
  return b * S_ + row * PS + col;
}

// ===== LN fused to bf16 (standalone, used once for ln1) =====
__global__ __launch_bounds__(256) void ln_k(const float* __restrict__ X,
                                            const float* __restrict__ g,
                                            const float* __restrict__ b,
                                            uint16_t* __restrict__ O) {
  int t = blockIdx.x * 4 + (threadIdx.x >> 6);
  int lane = threadIdx.x & 63;
  float2 v = *(const float2*)(X + (size_t)t * DIM + lane * 2);
  float s = v.x + v.y, sq = v.x * v.x + v.y * v.y;
  #pragma unroll
  for (int o = 32; o; o >>= 1) { s += __shfl_xor(s, o); sq += __shfl_xor(sq, o); }
  float mu = s * (1.0f / 128.0f);
  float rs = rsqrtf(sq * (1.0f / 128.0f) - mu * mu + 1e-5f);
  float2 gg = *(const float2*)(g + lane * 2);
  float2 bb = *(const float2*)(b + lane * 2);
  float a = (v.x - mu) * rs * gg.x + bb.x;
  float c = (v.y - mu) * rs * gg.y + bb.y;
  ((uint32_t*)O)[(size_t)t * 64 + lane] = bfpack(a, c);
}

// ===== one-shot weight conversion f32 -> bf16 =====
__global__ __launch_bounds__(256) void wconv_k(
    const float* __restrict__ w0, const float* __restrict__ w1,
    const float* __restrict__ w2, const float* __restrict__ w3,
    const float* __restrict__ w4, const float* __restrict__ w5,
    uint16_t* __restrict__ out) {
  int i = blockIdx.x * 256 + threadIdx.x;   // 0..163839
  float v;
  if      (i <  49152) v = w0[i];
  else if (i <  98304) v = w1[i -  49152];
  else if (i < 114688) v = w2[i -  98304];
  else if (i < 131072) v = w3[i - 114688];
  else if (i < 147456) v = w4[i - 131072];
  else                 v = w5[i - 147456];
  out[i] = bf16of(v);
}

// ================= MFMA GEMM (verified) — used for mlp2 (f32 out) =================
constexpr int MKC = 64, MKSTR = MKC + 8;

template<int IN_SHIFT, int OUT_SHIFT, bool RES, bool OUT_BF16>
__global__ __launch_bounds__(256) void gemm_m2(
    const uint16_t* __restrict__ A, const uint16_t* __restrict__ Wb,
    const float* __restrict__ bias, const float* __restrict__ Rsrc,
    void* __restrict__ Out, int Ncols)
{
  __shared__ __align__(16) uint16_t As[128][MKSTR];
  __shared__ __align__(16) uint16_t Ws[128][MKSTR];
  const int tid = threadIdx.x;
  const int lane = tid & 63;
  const int lanelow = lane & 15;
  const int quad = lane >> 4;
  const int wid = tid >> 6;
  const int wave_m = wid >> 1, wave_n = wid & 1;
  const int mtile = blockIdx.y * 128;
  const int ntile = blockIdx.x * 128;

  f32x4 acc[4][4];
  #pragma unroll
  for (int mt = 0; mt < 4; ++mt)
    #pragma unroll
    for (int nt = 0; nt < 4; ++nt) acc[mt][nt] = (f32x4){0.f, 0.f, 0.f, 0.f};

  for (int kc = 0; kc < DIM; kc += MKC) {
    #pragma unroll
    for (int it = 0; it < 8; ++it) {
      int idx = tid + it * 256;
      int m = idx >> 4;
      int k4 = (idx & 15) << 2;
      int gm = mtile + m;
      int src = (IN_SHIFT < 0) ? gm : win_map(gm, IN_SHIFT);
      *(uint2*)&As[m][k4] = *(const uint2*)(A + (size_t)src * DIM + kc + k4);
    }
    #pragma unroll
    for (int it = 0; it < 8; ++it) {
      int idx = tid + it * 256;
      int n = idx >> 4;
      int k4 = (idx & 15) << 2;
      *(uint2*)&Ws[n][k4] = *(const uint2*)(Wb + (size_t)(ntile + n) * DIM + kc + k4);
    }
    __syncthreads();
    #pragma unroll
    for (int k0 = 0; k0 < MKC; k0 += 32) {
      short8 af[4], bf[4];
      #pragma unroll
      for (int mt = 0; mt < 4; ++mt)
        af[mt] = *(const short8*)&As[wave_m * 64 + mt * 16 + lanelow][k0 + quad * 8];
      #pragma unroll
      for (int nt = 0; nt < 4; ++nt)
        bf[nt] = *(const short8*)&Ws[wave_n * 64 + nt * 16 + lanelow][k0 + quad * 8];
      #pragma unroll
      for (int mt = 0; mt < 4; ++mt)
        #pragma unroll
        for (int nt = 0; nt < 4; ++nt)
          acc[mt][nt] = __builtin_amdgcn_mfma_f32_16x16x32_bf16(af[mt], bf[nt], acc[mt][nt], 0, 0, 0);
    }
    __syncthreads();
  }
  #pragma unroll
  for (int nt = 0; nt < 4; ++nt) {
    int col = ntile + wave_n * 64 + nt * 16 + lanelow;
    float bb = bias[col];
    #pragma unroll
    for (int mt = 0; mt < 4; ++mt) {
      #pragma unroll
      for (int r = 0; r < 4; ++r) {
        int gm = mtile + wave_m * 64 + mt * 16 + quad * 4 + r;
        float v = acc[mt][nt][r] + bb;
        if constexpr (OUT_BF16) {
          ((uint16_t*)Out)[(size_t)gm * Ncols + col] = bf16of(v);
        } else {
          int orow = (OUT_SHIFT < 0) ? gm : win_map(gm, OUT_SHIFT);
          if constexpr (RES) v += Rsrc[(size_t)orow * DIM + col];
          ((float*)Out)[(size_t)orow * (size_t)Ncols + col] = v;
        }
      }
    }
  }
}

// ================= gemm_m3: mlp GEMM + bias + residual + fused next-LN =================
__global__ __launch_bounds__(256) void gemm_m3(
    const uint16_t* __restrict__ A, const uint16_t* __restrict__ Wb,
    const float* __restrict__ bias, const float* __restrict__ Rsrc,
    float* __restrict__ Xout, const float* __restrict__ lng,
    const float* __restrict__ lnb, uint16_t* __restrict__ xb)
{
  __shared__ __align__(16) uint16_t As[128][MKSTR];
  __shared__ __align__(16) uint16_t Ws[128][MKSTR];
  __shared__ float lnred[128][2][2];
  const int tid = threadIdx.x;
  const int lane = tid & 63;
  const int lanelow = lane & 15;
  const int quad = lane >> 4;
  const int wid = tid >> 6;
  const int wave_m = wid >> 1, wave_n = wid & 1;
  const int mtile = blockIdx.y * 128;

  f32x4 acc[4][4];
  #pragma unroll
  for (int mt = 0; mt < 4; ++mt)
    #pragma unroll
    for (int nt = 0; nt < 4; ++nt) acc[mt][nt] = (f32x4){0.f, 0.f, 0.f, 0.f};

  for (int kc = 0; kc < DIM; kc += MKC) {
    #pragma unroll
    for (int it = 0; it < 8; ++it) {
      int idx = tid + it * 256;
      int m = idx >> 4;
      int k4 = (idx & 15) << 2;
      *(uint2*)&As[m][k4] = *(const uint2*)(A + (size_t)(mtile + m) * DIM + kc + k4);
    }
    #pragma unroll
    for (int it = 0; it < 8; ++it) {
      int idx = tid + it * 256;
      int n = idx >> 4;
      int k4 = (idx & 15) << 2;
      *(uint2*)&Ws[n][k4] = *(const uint2*)(Wb + (size_t)n * DIM + kc + k4);
    }
    __syncthreads();
    #pragma unroll
    for (int k0 = 0; k0 < MKC; k0 += 32) {
      short8 af[4], bf[4];
      #pragma unroll
      for (int mt = 0; mt < 4; ++mt)
        af[mt] = *(const short8*)&As[wave_m * 64 + mt * 16 + lanelow][k0 + quad * 8];
      #pragma unroll
      for (int nt = 0; nt < 4; ++nt)
        bf[nt] = *(const short8*)&Ws[wave_n * 64 + nt * 16 + lanelow][k0 + quad * 8];
      #pragma unroll
      for (int mt = 0; mt < 4; ++mt)
        #pragma unroll
        for (int nt = 0; nt < 4; ++nt)
          acc[mt][nt] = __builtin_amdgcn_mfma_f32_16x16x32_bf16(af[mt], bf[nt], acc[mt][nt], 0, 0, 0);
    }
    __syncthreads();
  }
  float bb[4], gg[4], bt[4];
  #pragma unroll
  for (int nt = 0; nt < 4; ++nt) {
    int col = wave_n * 64 + nt * 16 + lanelow;
    bb[nt] = bias[col]; gg[nt] = lng[col]; bt[nt] = lnb[col];
  }
  #pragma unroll
  for (int mt = 0; mt < 4; ++mt)
    #pragma unroll
    for (int r = 0; r < 4; ++r) {
      int gm = mtile + wave_m * 64 + mt * 16 + quad * 4 + r;
      float s = 0.f, sq = 0.f;
      #pragma unroll
      for (int nt = 0; nt < 4; ++nt) {
        int col = wave_n * 64 + nt * 16 + lanelow;
        float v = acc[mt][nt][r] + bb[nt] + Rsrc[(size_t)gm * DIM + col];
        acc[mt][nt][r] = v;
        s += v; sq += v * v;
      }
      s += __shfl_xor(s, 1); sq += __shfl_xor(sq, 1);
      s += __shfl_xor(s, 2); sq += __shfl_xor(sq, 2);
      s += __shfl_xor(s, 4); sq += __shfl_xor(sq, 4);
      s += __shfl_xor(s, 8); sq += __shfl_xor(sq, 8);
      if (lanelow == 0) {
        int lr = wave_m * 64 + mt * 16 + quad * 4 + r;
        lnred[lr][wave_n][0] = s;
        lnred[lr][wave_n][1] = sq;
      }
    }
  __syncthreads();
  #pragma unroll
  for (int mt = 0; mt < 4; ++mt)
    #pragma unroll
    for (int r = 0; r < 4; ++r) {
      int lr = wave_m * 64 + mt * 16 + quad * 4 + r;
      int gm = mtile + lr;
      float s  = lnred[lr][0][0] + lnred[lr][1][0];
      float sq = lnred[lr][0][1] + lnred[lr][1][1];
      float mu = s * (1.0f / 128.0f);
      float rs = rsqrtf(sq * (1.0f / 128.0f) - mu * mu + 1e-5f);
      #pragma unroll
      for (int nt = 0; nt < 4; ++nt) {
        int col = wave_n * 64 + nt * 16 + lanelow;
        float v = acc[mt][nt][r];
        Xout[(size_t)gm * DIM + col] = v;
        xb[(size_t)gm * DIM + col] = bf16of((v - mu) * rs * gg[nt] + bt[nt]);
      }
    }
}

// ================= bias precompute: biasT[h][k][q], mask baked =================
__global__ __launch_bounds__(256) void bias_k(const float* __restrict__ tbl, float* __restrict__ biasT) {
  int idx = blockIdx.x * 256 + threadIdx.x;   // (h<<12 | k<<6 | q)
  int h = idx >> 12;
  int k = (idx >> 6) & 63;
  int q = idx & 63;
  float v;
  if (k >= 49)      v = -1e30f;
  else if (q >= 49) v = 0.f;
  else {
    int yi = q / 7, xi = q - yi * 7;
    int yj = k / 7, xj = k - yj * 7;
    v = tbl[((yi - yj + 6) * 13 + (xi - xj + 6)) * 4 + h];
  }
  biasT[idx] = v;
}

// ===== attn3: fused qkv-GEMM + QK^T + softmax + PV + Wo proj + residual + next-LN =====
// Each wave computes its own head's Q/K/V columns directly into qs (no qkvb roundtrip).
// No barrier between qkv phase and frag loads: each wave reads only columns it wrote.
constexpr int QKV_STR = 392;
constexpr int OS_STR  = 140;   // O tile stride (bf16): 70 dwords -> conflict-free frags

template<int IN_SHIFT, int OUT_SHIFT>
__global__ __launch_bounds__(256) void attn3(const uint16_t* __restrict__ xbin,
                                             const uint16_t* __restrict__ Wqkv,
                                             const float* __restrict__ bqkv,
                                             const float* __restrict__ biasT,
                                             const uint16_t* __restrict__ Wo,
                                             const float* __restrict__ bo,
                                             const float* __restrict__ Rsrc,
                                             float* __restrict__ Xout,
                                             const float* __restrict__ lng,
                                             const float* __restrict__ lnb,
                                             uint16_t* __restrict__ xbout)
{
  __shared__ __align__(16) uint16_t qs[64 * QKV_STR];   // qkv tile; rows 49..63 dup-row-48 pad
  __shared__ float lnred[64][4][2];
  const int tid = threadIdx.x;
  const int lane = tid & 63;
  const int h = tid >> 6;
  const int lanelow = lane & 15;
  const int quad = lane >> 4;
  const int base = blockIdx.x * 49;

  // ---- phase 0: qkv = xb@Wqkv^T + bqkv, straight into qs (verified gemm fragment conv) ----
  {
    short8 af[4][4];   // [mt][k0]: A rows mt*16+lanelow (clamped), k = k0*32+quad*8
    #pragma unroll
    for (int mt = 0; mt < 4; ++mt) {
      int tok = mt * 16 + lanelow; if (tok > 48) tok = 48;
      int src = win_map(base + tok, IN_SHIFT);
      const uint16_t* arow = xbin + (size_t)src * DIM;
      #pragma unroll
      for (int k0 = 0; k0 < 4; ++k0)
        af[mt][k0] = *(const short8*)(arow + k0 * 32 + quad * 8);
    }
    #pragma unroll
    for (int ntl = 0; ntl < 6; ++ntl) {
      // output col = W row: seg*128 + h*32 + (ntl&1)*16 + lanelow  (seg 0=q,1=k,2=v)
      int wrow = (ntl >> 1) * 128 + h * 32 + (ntl & 1) * 16 + lanelow;
      const uint16_t* wr_ = Wqkv + (size_t)wrow * DIM;
      short8 bfr[4];
      #pragma unroll
      for (int k0 = 0; k0 < 4; ++k0)
        bfr[k0] = *(const short8*)(wr_ + k0 * 32 + quad * 8);
      f32x4 a4[4];
      #pragma unroll
      for (int mt = 0; mt < 4; ++mt) a4[mt] = (f32x4){0.f, 0.f, 0.f, 0.f};
      #pragma unroll
      for (int k0 = 0; k0 < 4; ++k0)
        #pragma unroll
        for (int mt = 0; mt < 4; ++mt)
          a4[mt] = __builtin_amdgcn_mfma_f32_16x16x32_bf16(af[mt][k0], bfr[k0], a4[mt], 0, 0, 0);
      float bq = bqkv[wrow];
      #pragma unroll
      for (int mt = 0; mt < 4; ++mt)
        #pragma unroll
        for (int r = 0; r < 4; ++r)
          qs[(mt * 16 + quad * 4 + r) * QKV_STR + wrow] = bf16of(a4[mt][r] + bq);
    }
  }

  // ---- T14: prefetch residual + output-row indices (consumed 3 phases later) ----
  const int n0 = h * 32 + lanelow, n1 = n0 + 16;
  int   orow_a[4][4];
  float r0a[4][4], r1a[4][4];
  #pragma unroll
  for (int qt = 0; qt < 4; ++qt)
    #pragma unroll
    for (int r = 0; r < 4; ++r) {
      int q = qt * 16 + quad * 4 + r;
      bool ok = (q < 49);
      int wrow = base + (ok ? q : 0);
      int orow = (OUT_SHIFT < 0) ? wrow : win_map(wrow, OUT_SHIFT);
      orow_a[qt][r] = orow;
      r0a[qt][r] = ok ? Rsrc[(size_t)orow * DIM + n0] : 0.f;
      r1a[qt][r] = ok ? Rsrc[(size_t)orow * DIM + n1] : 0.f;
    }

  // ---- S^T = K·Q^T (each wave reads only its own columns of qs; no barrier needed) ----
  f32x4 sc[4][4];
  #pragma unroll
  for (int kt = 0; kt < 4; ++kt)
    #pragma unroll
    for (int qt = 0; qt < 4; ++qt) sc[kt][qt] = (f32x4){0.f, 0.f, 0.f, 0.f};
  {
    short8 kf[4], qf[4];
    const int kcol = 128 + h * 32 + quad * 8;
    const int qcol = h * 32 + quad * 8;
    #pragma unroll
    for (int t = 0; t < 4; ++t) {
      int tok = t * 16 + lanelow; if (tok > 48) tok = 48;
      kf[t] = *(const short8*)(qs + tok * QKV_STR + kcol);
      qf[t] = *(const short8*)(qs + tok * QKV_STR + qcol);
    }
    // all waves hold Q,K in regs; Q/K columns of qs become dead -> reusable for P
    __syncthreads();
    #pragma unroll
    for (int kt = 0; kt < 4; ++kt)
      #pragma unroll
      for (int qt = 0; qt < 4; ++qt)
        sc[kt][qt] = __builtin_amdgcn_mfma_f32_16x16x32_bf16(kf[kt], qf[qt], sc[kt][qt], 0, 0, 0);
  }

  // ---- scale + bias + softmax over k ----
  const float* bh = biasT + h * 4096;
  #pragma unroll
  for (int kt = 0; kt < 4; ++kt)
    #pragma unroll
    for (int r = 0; r < 4; ++r) {
      const float* br = bh + (kt * 16 + quad * 4 + r) * 64 + lanelow;
      #pragma unroll
      for (int qt = 0; qt < 4; ++qt)
        sc[kt][qt][r] = fmaf(sc[kt][qt][r], 0.17677669529663689f, br[qt * 16]);
    }
  #pragma unroll
  for (int qt = 0; qt < 4; ++qt) {
    float m = sc[0][qt][0];
    #pragma unroll
    for (int kt = 0; kt < 4; ++kt)
      #pragma unroll
      for (int r = 0; r < 4; ++r) m = fmaxf(m, sc[kt][qt][r]);
    m = fmaxf(m, __shfl_xor(m, 16));
    m = fmaxf(m, __shfl_xor(m, 32));
    float s = 0.f;
    #pragma unroll
    for (int kt = 0; kt < 4; ++kt)
      #pragma unroll
      for (int r = 0; r < 4; ++r) {
        float e = __expf(sc[kt][qt][r] - m);
        sc[kt][qt][r] = e;
        s += e;
      }
    s += __shfl_xor(s, 16);
    s += __shfl_xor(s, 32);
    float inv = 1.0f / s;
    #pragma unroll
    for (int kt = 0; kt < 4; ++kt)
      #pragma unroll
      for (int r = 0; r < 4; ++r) sc[kt][qt][r] *= inv;
  }

  // ---- P (bf16) -> transposed into dead Q/K cols: P[q][k] at qs[q*STR + h*64 + k] ----
  uint16_t* pw = qs + h * 64;
  #pragma unroll
  for (int qt = 0; qt < 4; ++qt)
    #pragma unroll
    for (int kt = 0; kt < 4; ++kt) {
      uint2 pk;
      pk.x = bfpack(sc[kt][qt][0], sc[kt][qt][1]);
      pk.y = bfpack(sc[kt][qt][2], sc[kt][qt][3]);
      *(uint2*)(pw + (qt * 16 + lanelow) * QKV_STR + kt * 16 + quad * 4) = pk;
    }

  // ---- O = P·V ----
  f32x4 oc[4][2];
  #pragma unroll
  for (int qt = 0; qt < 4; ++qt)
    #pragma unroll
    for (int dt = 0; dt < 2; ++dt) oc[qt][dt] = (f32x4){0.f, 0.f, 0.f, 0.f};
  {
    short8 pf[4][2];
    #pragma unroll
    for (int qt = 0; qt < 4; ++qt)
      #pragma unroll
      for (int kp = 0; kp < 2; ++kp)
        pf[qt][kp] = *(const short8*)(pw + (qt * 16 + lanelow) * QKV_STR + kp * 32 + quad * 8);
    short8 vf[2][2];
    #pragma unroll
    for (int dt = 0; dt < 2; ++dt)
      #pragma unroll
      for (int kp = 0; kp < 2; ++kp) {
        short8 b;
        #pragma unroll
        for (int j = 0; j < 8; ++j) {
          int tok = kp * 32 + quad * 8 + j; if (tok > 48) tok = 48;
          b[j] = (short)qs[tok * QKV_STR + 256 + h * 32 + dt * 16 + lanelow];
        }
        vf[dt][kp] = b;
      }
    #pragma unroll
    for (int qt = 0; qt < 4; ++qt)
      #pragma unroll
      for (int dt = 0; dt < 2; ++dt)
        #pragma unroll
        for (int kp = 0; kp < 2; ++kp)
          oc[qt][dt] = __builtin_amdgcn_mfma_f32_16x16x32_bf16(pf[qt][kp], vf[dt][kp], oc[qt][dt], 0, 0, 0);
  }

  // ---- O -> LDS (alias flat over qs; all qs reads complete) ----
  __syncthreads();
  uint16_t* Os = qs;
  #pragma unroll
  for (int qt = 0; qt < 4; ++qt)
    #pragma unroll
    for (int r = 0; r < 4; ++r) {
      int t = qt * 16 + quad * 4 + r;
      #pragma unroll
      for (int dt = 0; dt < 2; ++dt)
        Os[t * OS_STR + h * 32 + dt * 16 + lanelow] = bf16of(oc[qt][dt][r]);
    }
  __syncthreads();

  // ---- proj: rc = O @ Wo^T, this wave computes cols h*32..h*32+31 ----
  f32x4 rc[4][2];
  #pragma unroll
  for (int qt = 0; qt < 4; ++qt)
    #pragma unroll
    for (int dt = 0; dt < 2; ++dt) rc[qt][dt] = (f32x4){0.f, 0.f, 0.f, 0.f};
  #pragma unroll
  for (int kp = 0; kp < 4; ++kp) {
    short8 af[4];
    #pragma unroll
    for (int qt = 0; qt < 4; ++qt)
      af[qt] = *(const short8*)&Os[(qt * 16 + lanelow) * OS_STR + kp * 32 + quad * 8];
    short8 bfr[2];
    #pragma unroll
    for (int dt = 0; dt < 2; ++dt)
      bfr[dt] = *(const short8*)(Wo + (size_t)(h * 32 + dt * 16 + lanelow) * DIM + kp * 32 + quad * 8);
    #pragma unroll
    for (int qt = 0; qt < 4; ++qt)
      #pragma unroll
      for (int dt = 0; dt < 2; ++dt)
        rc[qt][dt] = __builtin_amdgcn_mfma_f32_16x16x32_bf16(af[qt], bfr[dt], rc[qt][dt], 0, 0, 0);
  }

  // ---- bias + residual (prefetched), per-row LN partials ----
  const float b0 = bo[n0], b1 = bo[n1];
  const float g0 = lng[n0], g1 = lng[n1];
  const float e0 = lnb[n0], e1 = lnb[n1];
  #pragma unroll
  for (int qt = 0; qt < 4; ++qt)
    #pragma unroll
    for (int r = 0; r < 4; ++r) {
      int q = qt * 16 + quad * 4 + r;
      float v0 = rc[qt][0][r] + b0 + r0a[qt][r];
      float v1 = rc[qt][1][r] + b1 + r1a[qt][r];
      rc[qt][0][r] = v0; rc[qt][1][r] = v1;
      float s = v0 + v1, sq = v0 * v0 + v1 * v1;
      s += __shfl_xor(s, 1); sq += __shfl_xor(sq, 1);
      s += __shfl_xor(s, 2); sq += __shfl_xor(sq, 2);
      s += __shfl_xor(s, 4); sq += __shfl_xor(sq, 4);
      s += __shfl_xor(s, 8); sq += __shfl_xor(sq, 8);
      if (lanelow == 0) { lnred[q][h][0] = s; lnred[q][h][1] = sq; }
    }
  __syncthreads();
  // ---- finalize: write f32 stream + LN-normalized bf16 ----
  #pragma unroll
  for (int qt = 0; qt < 4; ++qt)
    #pragma unroll
    for (int r = 0; r < 4; ++r) {
      int q = qt * 16 + quad * 4 + r;
      if (q < 49) {
        int orow = orow_a[qt][r];
        float s  = lnred[q][0][0] + lnred[q][1][0] + lnred[q][2][0] + lnred[q][3][0];
        float sq = lnred[q][0][1] + lnred[q][1][1] + lnred[q][2][1] + lnred[q][3][1];
        float mu = s * (1.0f / 128.0f);
        float rs = rsqrtf(sq * (1.0f / 128.0f) - mu * mu + 1e-5f);
        float v0 = rc[qt][0][r], v1 = rc[qt][1][r];
        Xout[(size_t)orow * DIM + n0] = v0;
        Xout[(size_t)orow * DIM + n1] = v1;
        xbout[(size_t)orow * DIM + n0] = bf16of((v0 - mu) * rs * g0 + e0);
        xbout[(size_t)orow * DIM + n1] = bf16of((v1 - mu) * rs * g1 + e1);
      }
    }
}

extern "C" void kernel_launch(void* const* d_in, const int* in_sizes, int n_in,
                              void* d_out, int out_size, void* d_ws, size_t ws_size,
                              hipStream_t stream) {
  const float* x0    = (const float*)d_in[0];
  const float* ln1g  = (const float*)d_in[1];
  const float* ln1b  = (const float*)d_in[2];
  const float* wqkv1 = (const float*)d_in[3];
  const float* bqkv1 = (const float*)d_in[4];
  const float* wo1   = (const float*)d_in[5];
  const float* bo1   = (const float*)d_in[6];
  const float* tbl1  = (const float*)d_in[7];
  const float* ln2g  = (const float*)d_in[8];
  const float* ln2b  = (const float*)d_in[9];
  const float* wm1   = (const float*)d_in[10];
  const float* bm1   = (const float*)d_in[11];
  const float* ln3g  = (const float*)d_in[12];
  const float* ln3b  = (const float*)d_in[13];
  const float* wqkv2 = (const float*)d_in[14];
  const float* bqkv2 = (const float*)d_in[15];
  const float* wo2   = (const float*)d_in[16];
  const float* bo2   = (const float*)d_in[17];
  const float* tbl2  = (const float*)d_in[18];
  const float* ln4g  = (const float*)d_in[19];
  const float* ln4b  = (const float*)d_in[20];
  const float* wm2   = (const float*)d_in[21];
  const float* bm2   = (const float*)d_in[22];

  char* ws = (char*)d_ws;
  size_t off = 0;
  uint16_t* xbA  = (uint16_t*)(ws + off); off += (size_t)NTOK * 128 * sizeof(uint16_t);
  uint16_t* xb2  = (uint16_t*)(ws + off); off += (size_t)NTOK * 128 * sizeof(uint16_t);
  float* biasT1  = (float*)(ws + off);    off += 16384 * sizeof(float);
  float* biasT2  = (float*)(ws + off);    off += 16384 * sizeof(float);
  uint16_t* wb   = (uint16_t*)(ws + off); off += 163840 * sizeof(uint16_t);
  if (ws_size < off) return;
  float* x1 = (float*)d_out;   // single f32 stream, in-place residual updates

  uint16_t* wqkv1b = wb;
  uint16_t* wqkv2b = wb + 49152;
  uint16_t* wo1b   = wb + 98304;
  uint16_t* wm1b   = wb + 114688;
  uint16_t* wo2b   = wb + 131072;
  uint16_t* wm2b   = wb + 147456;

  dim3 blk(256);
  dim3 lgrid(NTOK / 4);
  dim3 g1m(1, 1568);        // mlp: N=128
  dim3 agrid(4096);

  wconv_k<<<640, blk, 0, stream>>>(wqkv1, wqkv2, wo1, wm1, wo2, wm2, wb);
  bias_k<<<64, blk, 0, stream>>>(tbl1, biasT1);
  bias_k<<<64, blk, 0, stream>>>(tbl2, biasT2);

  // block 1: W-MSA (fused qkv+attn+proj+res+ln2). Faithful quirk: identity output rows.
  ln_k<<<lgrid, blk, 0, stream>>>(x0, ln1g, ln1b, xbA);
  attn3<0, -1><<<agrid, blk, 0, stream>>>(xbA, wqkv1b, bqkv1, biasT1, wo1b, bo1,
                                          x0, x1, ln2g, ln2b, xb2);
  // mlp1 + fused ln3 (in-place residual on x1; ln3 -> xbA)
  gemm_m3<<<g1m, blk, 0, stream>>>(xb2, wm1b, bm1, x1, x1, ln3g, ln3b, xbA);
  // block 2: SW-MSA (fused; in/out rows via win_map shift 3)
  attn3<3, 3><<<agrid, blk, 0, stream>>>(xbA, wqkv2b, bqkv2, biasT2, wo2b, bo2,
                                         x1, x1, ln4g, ln4b, xb2);
  // mlp2 -> final output (reads only xb2; overwriting the stream is safe)
  gemm_m2<-1, -1, false, false><<<g1m, blk, 0, stream>>>(xb2, wm2b, bm2, nullptr, d_out, 128);
}

// Round 7
// 698.125 us; speedup vs baseline: 2.9506x; 1.0184x over previous
//
#include <hip/hip_runtime.h>
#include <hip/hip_bf16.h>
#include <stdint.h>

#define PS 56
#define S_ 3136
#define DIM 128
#define NTOK 200704   // 64 * 3136

typedef __attribute__((ext_vector_type(8))) short short8;
typedef __attribute__((ext_vector_type(4))) float f32x4;

__device__ __forceinline__ uint32_t bfpack(float a, float b){
  uint32_t ua = __float_as_uint(a); ua = (ua + 0x7fffu + ((ua >> 16) & 1u)) >> 16;
  uint32_t ub = __float_as_uint(b); ub = (ub + 0x7fffu + ((ub >> 16) & 1u)) & 0xffff0000u;
  return ua | ub;
}
__device__ __forceinline__ uint16_t bf16of(float a){
  uint32_t ua = __float_as_uint(a);
  return (uint16_t)((ua + 0x7fffu + ((ua >> 16) & 1u)) >> 16);
}

__device__ __forceinline__ int win_map(int r, int shift) {
  int b = r / S_;
  int rem = r - b * S_;
  int w = rem / 49;
  int p = rem - w * 49;
  int i = p / 7, j = p - i * 7;
  int wr = w >> 3, wc = w & 7;
  int row = wr * 7 + i + shift; if (row >= PS) row -= PS;
  int col = wc * 7 + j + shift; if (col >= PS) col -= PS;
  return b * S_ + row * PS + col;
}

// ===== LN fused to bf16 (standalone, used once for ln1) =====
__global__ __launch_bounds__(256) void ln_k(const float* __restrict__ X,
                                            const float* __restrict__ g,
                                            const float* __restrict__ b,
                                            uint16_t* __restrict__ O) {
  int t = blockIdx.x * 4 + (threadIdx.x >> 6);
  int lane = threadIdx.x & 63;
  float2 v = *(const float2*)(X + (size_t)t * DIM + lane * 2);
  float s = v.x + v.y, sq = v.x * v.x + v.y * v.y;
  #pragma unroll
  for (int o = 32; o; o >>= 1) { s += __shfl_xor(s, o); sq += __shfl_xor(sq, o); }
  float mu = s * (1.0f / 128.0f);
  float rs = rsqrtf(sq * (1.0f / 128.0f) - mu * mu + 1e-5f);
  float2 gg = *(const float2*)(g + lane * 2);
  float2 bb = *(const float2*)(b + lane * 2);
  float a = (v.x - mu) * rs * gg.x + bb.x;
  float c = (v.y - mu) * rs * gg.y + bb.y;
  ((uint32_t*)O)[(size_t)t * 64 + lane] = bfpack(a, c);
}

// ===== one-shot weight conversion f32 -> bf16 =====
__global__ __launch_bounds__(256) void wconv_k(
    const float* __restrict__ w0, const float* __restrict__ w1,
    const float* __restrict__ w2, const float* __restrict__ w3,
    const float* __restrict__ w4, const float* __restrict__ w5,
    uint16_t* __restrict__ out) {
  int i = blockIdx.x * 256 + threadIdx.x;   // 0..163839
  float v;
  if      (i <  49152) v = w0[i];
  else if (i <  98304) v = w1[i -  49152];
  else if (i < 114688) v = w2[i -  98304];
  else if (i < 131072) v = w3[i - 114688];
  else if (i < 147456) v = w4[i - 131072];
  else                 v = w5[i - 147456];
  out[i] = bf16of(v);
}

// ================= gemm_d: direct-fragment GEMM (no LDS tiles), N=128 =================
// block = 64 rows, 4 waves; wave w -> cols w*32..w*32+31. Optional residual + fused LN.
template<bool RES, bool DOLN>
__global__ __launch_bounds__(256) void gemm_d(
    const uint16_t* __restrict__ A, const uint16_t* __restrict__ Wb,
    const float* __restrict__ bias, const float* __restrict__ Rsrc,
    float* __restrict__ Xout, const float* __restrict__ lng,
    const float* __restrict__ lnb, uint16_t* __restrict__ xbout)
{
  __shared__ float lnred[64][4][2];
  const int tid = threadIdx.x;
  const int lane = tid & 63;
  const int lanelow = lane & 15;
  const int quad = lane >> 4;
  const int w = tid >> 6;
  const int base = blockIdx.x * 64;

  short8 af[4][4];
  #pragma unroll
  for (int mt = 0; mt < 4; ++mt) {
    const uint16_t* arow = A + (size_t)(base + mt * 16 + lanelow) * DIM;
    #pragma unroll
    for (int k0 = 0; k0 < 4; ++k0)
      af[mt][k0] = *(const short8*)(arow + k0 * 32 + quad * 8);
  }
  f32x4 acc[4][2];
  #pragma unroll
  for (int mt = 0; mt < 4; ++mt)
    #pragma unroll
    for (int nt = 0; nt < 2; ++nt) acc[mt][nt] = (f32x4){0.f, 0.f, 0.f, 0.f};
  #pragma unroll
  for (int nt = 0; nt < 2; ++nt) {
    int wrow = w * 32 + nt * 16 + lanelow;
    const uint16_t* wr_ = Wb + (size_t)wrow * DIM;
    short8 bfr[4];
    #pragma unroll
    for (int k0 = 0; k0 < 4; ++k0)
      bfr[k0] = *(const short8*)(wr_ + k0 * 32 + quad * 8);
    #pragma unroll
    for (int k0 = 0; k0 < 4; ++k0)
      #pragma unroll
      for (int mt = 0; mt < 4; ++mt)
        acc[mt][nt] = __builtin_amdgcn_mfma_f32_16x16x32_bf16(af[mt][k0], bfr[k0], acc[mt][nt], 0, 0, 0);
  }
  const int n0 = w * 32 + lanelow, n1 = n0 + 16;
  const float b0 = bias[n0], b1 = bias[n1];
  float g0, g1, e0, e1;
  if constexpr (DOLN) { g0 = lng[n0]; g1 = lng[n1]; e0 = lnb[n0]; e1 = lnb[n1]; }
  #pragma unroll
  for (int mt = 0; mt < 4; ++mt)
    #pragma unroll
    for (int r = 0; r < 4; ++r) {
      int row = mt * 16 + quad * 4 + r;
      int gm = base + row;
      float v0 = acc[mt][0][r] + b0;
      float v1 = acc[mt][1][r] + b1;
      if constexpr (RES) {
        v0 += Rsrc[(size_t)gm * DIM + n0];
        v1 += Rsrc[(size_t)gm * DIM + n1];
      }
      acc[mt][0][r] = v0; acc[mt][1][r] = v1;
      if constexpr (DOLN) {
        float s = v0 + v1, sq = v0 * v0 + v1 * v1;
        s += __shfl_xor(s, 1); sq += __shfl_xor(sq, 1);
        s += __shfl_xor(s, 2); sq += __shfl_xor(sq, 2);
        s += __shfl_xor(s, 4); sq += __shfl_xor(sq, 4);
        s += __shfl_xor(s, 8); sq += __shfl_xor(sq, 8);
        if (lanelow == 0) { lnred[row][w][0] = s; lnred[row][w][1] = sq; }
      } else {
        Xout[(size_t)gm * DIM + n0] = v0;
        Xout[(size_t)gm * DIM + n1] = v1;
      }
    }
  if constexpr (DOLN) {
    __syncthreads();
    #pragma unroll
    for (int mt = 0; mt < 4; ++mt)
      #pragma unroll
      for (int r = 0; r < 4; ++r) {
        int row = mt * 16 + quad * 4 + r;
        int gm = base + row;
        float s  = lnred[row][0][0] + lnred[row][1][0] + lnred[row][2][0] + lnred[row][3][0];
        float sq = lnred[row][0][1] + lnred[row][1][1] + lnred[row][2][1] + lnred[row][3][1];
        float mu = s * (1.0f / 128.0f);
        float rs = rsqrtf(sq * (1.0f / 128.0f) - mu * mu + 1e-5f);
        float v0 = acc[mt][0][r], v1 = acc[mt][1][r];
        Xout[(size_t)gm * DIM + n0] = v0;
        Xout[(size_t)gm * DIM + n1] = v1;
        xbout[(size_t)gm * DIM + n0] = bf16of((v0 - mu) * rs * g0 + e0);
        xbout[(size_t)gm * DIM + n1] = bf16of((v1 - mu) * rs * g1 + e1);
      }
  }
}

// ================= bias precompute: biasT[h][k][q], mask baked =================
__global__ __launch_bounds__(256) void bias_k(const float* __restrict__ tbl, float* __restrict__ biasT) {
  int idx = blockIdx.x * 256 + threadIdx.x;   // (h<<12 | k<<6 | q)
  int h = idx >> 12;
  int k = (idx >> 6) & 63;
  int q = idx & 63;
  float v;
  if (k >= 49)      v = -1e30f;
  else if (q >= 49) v = 0.f;
  else {
    int yi = q / 7, xi = q - yi * 7;
    int yj = k / 7, xj = k - yj * 7;
    v = tbl[((yi - yj + 6) * 13 + (xi - xj + 6)) * 4 + h];
  }
  biasT[idx] = v;
}

// ===== attn3: fused qkv + QK^T + softmax + PV + Wo proj + residual + next-LN =====
// Q/K computed operand-SWAPPED -> vector uint2 stores into row-major qk_s[tok][d0..255].
// V computed normally -> vector stores into col-major vT[d][tok] -> b128 PV reads.
constexpr int QKSTR = 264;   // 132 dwords = 4 mod 32 -> conflict-clean b128 rows
constexpr int VSTR  = 72;    // 36 dwords = 4 mod 32; mult of 8 -> 16B-aligned b128
constexpr int OS_STR = 140;  // O tile stride (bf16), aliases qk_s

template<int IN_SHIFT, int OUT_SHIFT>
__global__ __launch_bounds__(256) void attn3(const uint16_t* __restrict__ xbin,
                                             const uint16_t* __restrict__ Wqkv,
                                             const float* __restrict__ bqkv,
                                             const float* __restrict__ biasT,
                                             const uint16_t* __restrict__ Wo,
                                             const float* __restrict__ bo,
                                             const float* __restrict__ Rsrc,
                                             float* __restrict__ Xout,
                                             const float* __restrict__ lng,
                                             const float* __restrict__ lnb,
                                             uint16_t* __restrict__ xbout)
{
  __shared__ __align__(16) uint16_t qk_s[64 * QKSTR];  // 33,792 B: Q(0..127)|K(128..255), row=tok
  __shared__ __align__(16) uint16_t vT[128 * VSTR];    // 18,432 B: V col-major [d][tok]
  __shared__ float lnred[64][4][2];                    //  2,048 B   (total 54,272 B -> 3 blk/CU)
  const int tid = threadIdx.x;
  const int lane = tid & 63;
  const int h = tid >> 6;
  const int lanelow = lane & 15;
  const int quad = lane >> 4;
  const int base = blockIdx.x * 49;

  // ---- phase 0: qkv = xb@Wqkv^T + bqkv ----
  {
    short8 af[4][4];   // x fragments: rows mt*16+lanelow (clamped), k = k0*32+quad*8
    #pragma unroll
    for (int mt = 0; mt < 4; ++mt) {
      int tok = mt * 16 + lanelow; if (tok > 48) tok = 48;
      int src = win_map(base + tok, IN_SHIFT);
      const uint16_t* arow = xbin + (size_t)src * DIM;
      #pragma unroll
      for (int k0 = 0; k0 < 4; ++k0)
        af[mt][k0] = *(const short8*)(arow + k0 * 32 + quad * 8);
    }
    // Q,K: swapped operands -> C(row=d=quad*4+r, col=tok=lanelow) -> uint2 stores
    #pragma unroll
    for (int ntl = 0; ntl < 4; ++ntl) {
      int dbase = (ntl >> 1) * 128 + h * 32 + (ntl & 1) * 16;   // 0..255
      const uint16_t* wr_ = Wqkv + (size_t)(dbase + lanelow) * DIM;
      short8 bfr[4];
      #pragma unroll
      for (int k0 = 0; k0 < 4; ++k0)
        bfr[k0] = *(const short8*)(wr_ + k0 * 32 + quad * 8);
      f32x4 a4[4];
      #pragma unroll
      for (int mt = 0; mt < 4; ++mt) a4[mt] = (f32x4){0.f, 0.f, 0.f, 0.f};
      #pragma unroll
      for (int k0 = 0; k0 < 4; ++k0)
        #pragma unroll
        for (int mt = 0; mt < 4; ++mt)
          a4[mt] = __builtin_amdgcn_mfma_f32_16x16x32_bf16(bfr[k0], af[mt][k0], a4[mt], 0, 0, 0);
      float4 bq4 = *(const float4*)(bqkv + dbase + quad * 4);
      #pragma unroll
      for (int mt = 0; mt < 4; ++mt) {
        uint2 pk;
        pk.x = bfpack(a4[mt][0] + bq4.x, a4[mt][1] + bq4.y);
        pk.y = bfpack(a4[mt][2] + bq4.z, a4[mt][3] + bq4.w);
        *(uint2*)(qk_s + (mt * 16 + lanelow) * QKSTR + dbase + quad * 4) = pk;
      }
    }
    // V: original operands -> C(row=tok=quad*4+r, col=d=lanelow) -> uint2 stores col-major
    #pragma unroll
    for (int ntl = 0; ntl < 2; ++ntl) {
      int wrow = 256 + h * 32 + ntl * 16 + lanelow;
      const uint16_t* wr_ = Wqkv + (size_t)wrow * DIM;
      short8 bfr[4];
      #pragma unroll
      for (int k0 = 0; k0 < 4; ++k0)
        bfr[k0] = *(const short8*)(wr_ + k0 * 32 + quad * 8);
      f32x4 a4[4];
      #pragma unroll
      for (int mt = 0; mt < 4; ++mt) a4[mt] = (f32x4){0.f, 0.f, 0.f, 0.f};
      #pragma unroll
      for (int k0 = 0; k0 < 4; ++k0)
        #pragma unroll
        for (int mt = 0; mt < 4; ++mt)
          a4[mt] = __builtin_amdgcn_mfma_f32_16x16x32_bf16(af[mt][k0], bfr[k0], a4[mt], 0, 0, 0);
      float bq = bqkv[wrow];
      int vd = h * 32 + ntl * 16 + lanelow;
      #pragma unroll
      for (int mt = 0; mt < 4; ++mt) {
        uint2 pk;
        pk.x = bfpack(a4[mt][0] + bq, a4[mt][1] + bq);
        pk.y = bfpack(a4[mt][2] + bq, a4[mt][3] + bq);
        *(uint2*)(vT + (size_t)vd * VSTR + mt * 16 + quad * 4) = pk;
      }
    }
  }

  // ---- T14: prefetch residual + output-row indices ----
  const int n0 = h * 32 + lanelow, n1 = n0 + 16;
  int   orow_a[4][4];
  float r0a[4][4], r1a[4][4];
  #pragma unroll
  for (int qt = 0; qt < 4; ++qt)
    #pragma unroll
    for (int r = 0; r < 4; ++r) {
      int q = qt * 16 + quad * 4 + r;
      bool ok = (q < 49);
      int wrow = base + (ok ? q : 0);
      int orow = (OUT_SHIFT < 0) ? wrow : win_map(wrow, OUT_SHIFT);
      orow_a[qt][r] = orow;
      r0a[qt][r] = ok ? Rsrc[(size_t)orow * DIM + n0] : 0.f;
      r1a[qt][r] = ok ? Rsrc[(size_t)orow * DIM + n1] : 0.f;
    }

  // ---- S^T = K·Q^T (each wave reads only cols it wrote; barrier after reg loads) ----
  f32x4 sc[4][4];
  #pragma unroll
  for (int kt = 0; kt < 4; ++kt)
    #pragma unroll
    for (int qt = 0; qt < 4; ++qt) sc[kt][qt] = (f32x4){0.f, 0.f, 0.f, 0.f};
  {
    short8 kf[4], qf[4];
    const int kcol = 128 + h * 32 + quad * 8;
    const int qcol = h * 32 + quad * 8;
    #pragma unroll
    for (int t = 0; t < 4; ++t) {
      int tok = t * 16 + lanelow; if (tok > 48) tok = 48;
      kf[t] = *(const short8*)(qk_s + tok * QKSTR + kcol);
      qf[t] = *(const short8*)(qk_s + tok * QKSTR + qcol);
    }
    // all waves hold Q,K in regs; Q/K cols of qk_s become dead -> reusable for P
    __syncthreads();
    #pragma unroll
    for (int kt = 0; kt < 4; ++kt)
      #pragma unroll
      for (int qt = 0; qt < 4; ++qt)
        sc[kt][qt] = __builtin_amdgcn_mfma_f32_16x16x32_bf16(kf[kt], qf[qt], sc[kt][qt], 0, 0, 0);
  }

  // ---- scale + bias + softmax over k ----
  const float* bh = biasT + h * 4096;
  #pragma unroll
  for (int kt = 0; kt < 4; ++kt)
    #pragma unroll
    for (int r = 0; r < 4; ++r) {
      const float* br = bh + (kt * 16 + quad * 4 + r) * 64 + lanelow;
      #pragma unroll
      for (int qt = 0; qt < 4; ++qt)
        sc[kt][qt][r] = fmaf(sc[kt][qt][r], 0.17677669529663689f, br[qt * 16]);
    }
  #pragma unroll
  for (int qt = 0; qt < 4; ++qt) {
    float m = sc[0][qt][0];
    #pragma unroll
    for (int kt = 0; kt < 4; ++kt)
      #pragma unroll
      for (int r = 0; r < 4; ++r) m = fmaxf(m, sc[kt][qt][r]);
    m = fmaxf(m, __shfl_xor(m, 16));
    m = fmaxf(m, __shfl_xor(m, 32));
    float s = 0.f;
    #pragma unroll
    for (int kt = 0; kt < 4; ++kt)
      #pragma unroll
      for (int r = 0; r < 4; ++r) {
        float e = __expf(sc[kt][qt][r] - m);
        sc[kt][qt][r] = e;
        s += e;
      }
    s += __shfl_xor(s, 16);
    s += __shfl_xor(s, 32);
    float inv = 1.0f / s;
    #pragma unroll
    for (int kt = 0; kt < 4; ++kt)
      #pragma unroll
      for (int r = 0; r < 4; ++r) sc[kt][qt][r] *= inv;
  }

  // ---- P (bf16) -> dead Q/K cols: P[q][k] at qk_s[q*QKSTR + h*64 + k] ----
  uint16_t* pw = qk_s + h * 64;
  #pragma unroll
  for (int qt = 0; qt < 4; ++qt)
    #pragma unroll
    for (int kt = 0; kt < 4; ++kt) {
      uint2 pk;
      pk.x = bfpack(sc[kt][qt][0], sc[kt][qt][1]);
      pk.y = bfpack(sc[kt][qt][2], sc[kt][qt][3]);
      *(uint2*)(pw + (qt * 16 + lanelow) * QKSTR + kt * 16 + quad * 4) = pk;
    }

  // ---- O = P·V (V via b128 reads from vT) ----
  f32x4 oc[4][2];
  #pragma unroll
  for (int qt = 0; qt < 4; ++qt)
    #pragma unroll
    for (int dt = 0; dt < 2; ++dt) oc[qt][dt] = (f32x4){0.f, 0.f, 0.f, 0.f};
  {
    short8 pf[4][2];
    #pragma unroll
    for (int qt = 0; qt < 4; ++qt)
      #pragma unroll
      for (int kp = 0; kp < 2; ++kp)
        pf[qt][kp] = *(const short8*)(pw + (qt * 16 + lanelow) * QKSTR + kp * 32 + quad * 8);
    short8 vf[2][2];
    #pragma unroll
    for (int dt = 0; dt < 2; ++dt)
      #pragma unroll
      for (int kp = 0; kp < 2; ++kp)
        vf[dt][kp] = *(const short8*)(vT + (size_t)(h * 32 + dt * 16 + lanelow) * VSTR + kp * 32 + quad * 8);
    #pragma unroll
    for (int qt = 0; qt < 4; ++qt)
      #pragma unroll
      for (int dt = 0; dt < 2; ++dt)
        #pragma unroll
        for (int kp = 0; kp < 2; ++kp)
          oc[qt][dt] = __builtin_amdgcn_mfma_f32_16x16x32_bf16(pf[qt][kp], vf[dt][kp], oc[qt][dt], 0, 0, 0);
  }
  // P rows 49..63 are pad; V toks 49..63 dup row 48 — both only affect O rows q>=49,
  // which are never written out.

  // ---- O -> LDS (alias flat over qk_s; all qk_s/vT reads complete) ----
  __syncthreads();
  uint16_t* Os = qk_s;
  #pragma unroll
  for (int qt = 0; qt < 4; ++qt)
    #pragma unroll
    for (int r = 0; r < 4; ++r) {
      int t = qt * 16 + quad * 4 + r;
      #pragma unroll
      for (int dt = 0; dt < 2; ++dt)
        Os[t * OS_STR + h * 32 + dt * 16 + lanelow] = bf16of(oc[qt][dt][r]);
    }
  __syncthreads();

  // ---- proj: rc = O @ Wo^T, this wave computes cols h*32..h*32+31 ----
  f32x4 rc[4][2];
  #pragma unroll
  for (int qt = 0; qt < 4; ++qt)
    #pragma unroll
    for (int dt = 0; dt < 2; ++dt) rc[qt][dt] = (f32x4){0.f, 0.f, 0.f, 0.f};
  #pragma unroll
  for (int kp = 0; kp < 4; ++kp) {
    short8 af[4];
    #pragma unroll
    for (int qt = 0; qt < 4; ++qt)
      af[qt] = *(const short8*)&Os[(qt * 16 + lanelow) * OS_STR + kp * 32 + quad * 8];
    short8 bfr[2];
    #pragma unroll
    for (int dt = 0; dt < 2; ++dt)
      bfr[dt] = *(const short8*)(Wo + (size_t)(h * 32 + dt * 16 + lanelow) * DIM + kp * 32 + quad * 8);
    #pragma unroll
    for (int qt = 0; qt < 4; ++qt)
      #pragma unroll
      for (int dt = 0; dt < 2; ++dt)
        rc[qt][dt] = __builtin_amdgcn_mfma_f32_16x16x32_bf16(af[qt], bfr[dt], rc[qt][dt], 0, 0, 0);
  }

  // ---- bias + residual (prefetched), per-row LN partials ----
  const float b0 = bo[n0], b1 = bo[n1];
  const float g0 = lng[n0], g1 = lng[n1];
  const float e0 = lnb[n0], e1 = lnb[n1];
  #pragma unroll
  for (int qt = 0; qt < 4; ++qt)
    #pragma unroll
    for (int r = 0; r < 4; ++r) {
      int q = qt * 16 + quad * 4 + r;
      float v0 = rc[qt][0][r] + b0 + r0a[qt][r];
      float v1 = rc[qt][1][r] + b1 + r1a[qt][r];
      rc[qt][0][r] = v0; rc[qt][1][r] = v1;
      float s = v0 + v1, sq = v0 * v0 + v1 * v1;
      s += __shfl_xor(s, 1); sq += __shfl_xor(sq, 1);
      s += __shfl_xor(s, 2); sq += __shfl_xor(sq, 2);
      s += __shfl_xor(s, 4); sq += __shfl_xor(sq, 4);
      s += __shfl_xor(s, 8); sq += __shfl_xor(sq, 8);
      if (lanelow == 0) { lnred[q][h][0] = s; lnred[q][h][1] = sq; }
    }
  __syncthreads();
  // ---- finalize: write f32 stream + LN-normalized bf16 ----
  #pragma unroll
  for (int qt = 0; qt < 4; ++qt)
    #pragma unroll
    for (int r = 0; r < 4; ++r) {
      int q = qt * 16 + quad * 4 + r;
      if (q < 49) {
        int orow = orow_a[qt][r];
        float s  = lnred[q][0][0] + lnred[q][1][0] + lnred[q][2][0] + lnred[q][3][0];
        float sq = lnred[q][0][1] + lnred[q][1][1] + lnred[q][2][1] + lnred[q][3][1];
        float mu = s * (1.0f / 128.0f);
        float rs = rsqrtf(sq * (1.0f / 128.0f) - mu * mu + 1e-5f);
        float v0 = rc[qt][0][r], v1 = rc[qt][1][r];
        Xout[(size_t)orow * DIM + n0] = v0;
        Xout[(size_t)orow * DIM + n1] = v1;
        xbout[(size_t)orow * DIM + n0] = bf16of((v0 - mu) * rs * g0 + e0);
        xbout[(size_t)orow * DIM + n1] = bf16of((v1 - mu) * rs * g1 + e1);
      }
    }
}

extern "C" void kernel_launch(void* const* d_in, const int* in_sizes, int n_in,
                              void* d_out, int out_size, void* d_ws, size_t ws_size,
                              hipStream_t stream) {
  const float* x0    = (const float*)d_in[0];
  const float* ln1g  = (const float*)d_in[1];
  const float* ln1b  = (const float*)d_in[2];
  const float* wqkv1 = (const float*)d_in[3];
  const float* bqkv1 = (const float*)d_in[4];
  const float* wo1   = (const float*)d_in[5];
  const float* bo1   = (const float*)d_in[6];
  const float* tbl1  = (const float*)d_in[7];
  const float* ln2g  = (const float*)d_in[8];
  const float* ln2b  = (const float*)d_in[9];
  const float* wm1   = (const float*)d_in[10];
  const float* bm1   = (const float*)d_in[11];
  const float* ln3g  = (const float*)d_in[12];
  const float* ln3b  = (const float*)d_in[13];
  const float* wqkv2 = (const float*)d_in[14];
  const float* bqkv2 = (const float*)d_in[15];
  const float* wo2   = (const float*)d_in[16];
  const float* bo2   = (const float*)d_in[17];
  const float* tbl2  = (const float*)d_in[18];
  const float* ln4g  = (const float*)d_in[19];
  const float* ln4b  = (const float*)d_in[20];
  const float* wm2   = (const float*)d_in[21];
  const float* bm2   = (const float*)d_in[22];

  char* ws = (char*)d_ws;
  size_t off = 0;
  uint16_t* xbA  = (uint16_t*)(ws + off); off += (size_t)NTOK * 128 * sizeof(uint16_t);
  uint16_t* xb2  = (uint16_t*)(ws + off); off += (size_t)NTOK * 128 * sizeof(uint16_t);
  float* biasT1  = (float*)(ws + off);    off += 16384 * sizeof(float);
  float* biasT2  = (float*)(ws + off);    off += 16384 * sizeof(float);
  uint16_t* wb   = (uint16_t*)(ws + off); off += 163840 * sizeof(uint16_t);
  if (ws_size < off) return;
  float* x1 = (float*)d_out;   // single f32 stream, in-place residual updates

  uint16_t* wqkv1b = wb;
  uint16_t* wqkv2b = wb + 49152;
  uint16_t* wo1b   = wb + 98304;
  uint16_t* wm1b   = wb + 114688;
  uint16_t* wo2b   = wb + 131072;
  uint16_t* wm2b   = wb + 147456;

  dim3 blk(256);
  dim3 lgrid(NTOK / 4);
  dim3 dgrid(NTOK / 64);    // direct GEMM: 3136 blocks x 64 rows
  dim3 agrid(4096);

  wconv_k<<<640, blk, 0, stream>>>(wqkv1, wqkv2, wo1, wm1, wo2, wm2, wb);
  bias_k<<<64, blk, 0, stream>>>(tbl1, biasT1);
  bias_k<<<64, blk, 0, stream>>>(tbl2, biasT2);

  // block 1: W-MSA (fused qkv+attn+proj+res+ln2). Faithful quirk: identity output rows.
  ln_k<<<lgrid, blk, 0, stream>>>(x0, ln1g, ln1b, xbA);
  attn3<0, -1><<<agrid, blk, 0, stream>>>(xbA, wqkv1b, bqkv1, biasT1, wo1b, bo1,
                                          x0, x1, ln2g, ln2b, xb2);
  // mlp1 + residual + fused ln3 (in-place on x1; ln3 -> xbA)
  gemm_d<true, true><<<dgrid, blk, 0, stream>>>(xb2, wm1b, bm1, x1, x1, ln3g, ln3b, xbA);
  // block 2: SW-MSA (fused; in/out rows via win_map shift 3)
  attn3<3, 3><<<agrid, blk, 0, stream>>>(xbA, wqkv2b, bqkv2, biasT2, wo2b, bo2,
                                         x1, x1, ln4g, ln4b, xb2);
  // mlp2 -> final output (no residual per source quirk; reads only xb2)
  gemm_d<false, false><<<dgrid, blk, 0, stream>>>(xb2, wm2b, bm2, nullptr, (float*)d_out,
                                                  nullptr, nullptr, nullptr);
}

// Round 8
// 662.277 us; speedup vs baseline: 3.1103x; 1.0541x over previous
//
#include <hip/hip_runtime.h>
#include <hip/hip_bf16.h>
#include <stdint.h>

#define PS 56
#define S_ 3136
#define DIM 128
#define NTOK 200704   // 64 * 3136

typedef __attribute__((ext_vector_type(8))) short short8;
typedef __attribute__((ext_vector_type(4))) float f32x4;

__device__ __forceinline__ uint32_t bfpack(float a, float b){
  uint32_t ua = __float_as_uint(a); ua = (ua + 0x7fffu + ((ua >> 16) & 1u)) >> 16;
  uint32_t ub = __float_as_uint(b); ub = (ub + 0x7fffu + ((ub >> 16) & 1u)) & 0xffff0000u;
  return ua | ub;
}
__device__ __forceinline__ uint16_t bf16of(float a){
  uint32_t ua = __float_as_uint(a);
  return (uint16_t)((ua + 0x7fffu + ((ua >> 16) & 1u)) >> 16);
}

__device__ __forceinline__ int win_map(int r, int shift) {
  int b = r / S_;
  int rem = r - b * S_;
  int w = rem / 49;
  int p = rem - w * 49;
  int i = p / 7, j = p - i * 7;
  int wr = w >> 3, wc = w & 7;
  int row = wr * 7 + i + shift; if (row >= PS) row -= PS;
  int col = wc * 7 + j + shift; if (col >= PS) col -= PS;
  return b * S_ + row * PS + col;
}

// ===== LN fused to bf16 (standalone, used once for ln1) =====
__global__ __launch_bounds__(256) void ln_k(const float* __restrict__ X,
                                            const float* __restrict__ g,
                                            const float* __restrict__ b,
                                            uint16_t* __restrict__ O) {
  int t = blockIdx.x * 4 + (threadIdx.x >> 6);
  int lane = threadIdx.x & 63;
  float2 v = *(const float2*)(X + (size_t)t * DIM + lane * 2);
  float s = v.x + v.y, sq = v.x * v.x + v.y * v.y;
  #pragma unroll
  for (int o = 32; o; o >>= 1) { s += __shfl_xor(s, o); sq += __shfl_xor(sq, o); }
  float mu = s * (1.0f / 128.0f);
  float rs = rsqrtf(sq * (1.0f / 128.0f) - mu * mu + 1e-5f);
  float2 gg = *(const float2*)(g + lane * 2);
  float2 bb = *(const float2*)(b + lane * 2);
  float a = (v.x - mu) * rs * gg.x + bb.x;
  float c = (v.y - mu) * rs * gg.y + bb.y;
  ((uint32_t*)O)[(size_t)t * 64 + lane] = bfpack(a, c);
}

// ===== one-shot weight conversion f32 -> bf16 =====
__global__ __launch_bounds__(256) void wconv_k(
    const float* __restrict__ w0, const float* __restrict__ w1,
    const float* __restrict__ w2, const float* __restrict__ w3,
    const float* __restrict__ w4, const float* __restrict__ w5,
    uint16_t* __restrict__ out) {
  int i = blockIdx.x * 256 + threadIdx.x;   // 0..163839
  float v;
  if      (i <  49152) v = w0[i];
  else if (i <  98304) v = w1[i -  49152];
  else if (i < 114688) v = w2[i -  98304];
  else if (i < 131072) v = w3[i - 114688];
  else if (i < 147456) v = w4[i - 131072];
  else                 v = w5[i - 147456];
  out[i] = bf16of(v);
}

// ================= bias precompute: biasT[h][k][q], mask baked =================
__global__ __launch_bounds__(256) void bias_k(const float* __restrict__ tbl, float* __restrict__ biasT) {
  int idx = blockIdx.x * 256 + threadIdx.x;   // (h<<12 | k<<6 | q)
  int h = idx >> 12;
  int k = (idx >> 6) & 63;
  int q = idx & 63;
  float v;
  if (k >= 49)      v = -1e30f;
  else if (q >= 49) v = 0.f;
  else {
    int yi = q / 7, xi = q - yi * 7;
    int yj = k / 7, xj = k - yj * 7;
    v = tbl[((yi - yj + 6) * 13 + (xi - xj + 6)) * 4 + h];
  }
  biasT[idx] = v;
}

// ===== attn4: fused qkv + QK^T + softmax + PV + Wo proj + residual + LN + MLP =====
// Attention core is the round-5-verified layout (scalar qkv stores, P in dead Q/K cols,
// scalar V gather). New: after the attn-LN, the normalized tile goes to LDS (dead Os
// region) and the mlp GEMM runs in-block. MLP_LN=true additionally adds the stream
// residual and computes the post-mlp LN (ln3), writing both f32 stream and bf16 norm.
constexpr int QKV_STR = 392;
constexpr int OS_STR  = 140;   // O / X_lds tile stride (bf16), aliases qs

template<int IN_SHIFT, int OUT_SHIFT, bool MLP_LN>
__global__ __launch_bounds__(256) void attn4(const uint16_t* __restrict__ xbin,
                                             const uint16_t* __restrict__ Wqkv,
                                             const float* __restrict__ bqkv,
                                             const float* __restrict__ biasT,
                                             const uint16_t* __restrict__ Wo,
                                             const float* __restrict__ bo,
                                             const float* __restrict__ Rsrc,
                                             const uint16_t* __restrict__ Wm,
                                             const float* __restrict__ bm,
                                             const float* __restrict__ lnga,
                                             const float* __restrict__ lnba,
                                             const float* __restrict__ lngp,
                                             const float* __restrict__ lnbp,
                                             float* __restrict__ Xout,
                                             uint16_t* __restrict__ xbout)
{
  __shared__ __align__(16) uint16_t qs[64 * QKV_STR];   // qkv tile; rows 49..63 pad scratch
  __shared__ float lnred[64][4][2];
  const int tid = threadIdx.x;
  const int lane = tid & 63;
  const int h = tid >> 6;
  const int lanelow = lane & 15;
  const int quad = lane >> 4;
  const int base = blockIdx.x * 49;

  // ---- phase 0: qkv = xb@Wqkv^T + bqkv, straight into qs (r5-verified layout) ----
  {
    short8 af[4][4];
    #pragma unroll
    for (int mt = 0; mt < 4; ++mt) {
      int tok = mt * 16 + lanelow; if (tok > 48) tok = 48;
      int src = win_map(base + tok, IN_SHIFT);
      const uint16_t* arow = xbin + (size_t)src * DIM;
      #pragma unroll
      for (int k0 = 0; k0 < 4; ++k0)
        af[mt][k0] = *(const short8*)(arow + k0 * 32 + quad * 8);
    }
    #pragma unroll
    for (int ntl = 0; ntl < 6; ++ntl) {
      int wrow = (ntl >> 1) * 128 + h * 32 + (ntl & 1) * 16 + lanelow;
      const uint16_t* wr_ = Wqkv + (size_t)wrow * DIM;
      short8 bfr[4];
      #pragma unroll
      for (int k0 = 0; k0 < 4; ++k0)
        bfr[k0] = *(const short8*)(wr_ + k0 * 32 + quad * 8);
      f32x4 a4[4];
      #pragma unroll
      for (int mt = 0; mt < 4; ++mt) a4[mt] = (f32x4){0.f, 0.f, 0.f, 0.f};
      #pragma unroll
      for (int k0 = 0; k0 < 4; ++k0)
        #pragma unroll
        for (int mt = 0; mt < 4; ++mt)
          a4[mt] = __builtin_amdgcn_mfma_f32_16x16x32_bf16(af[mt][k0], bfr[k0], a4[mt], 0, 0, 0);
      float bq = bqkv[wrow];
      #pragma unroll
      for (int mt = 0; mt < 4; ++mt)
        #pragma unroll
        for (int r = 0; r < 4; ++r)
          qs[(mt * 16 + quad * 4 + r) * QKV_STR + wrow] = bf16of(a4[mt][r] + bq);
    }
  }

  // ---- T14: prefetch residual + output-row indices ----
  const int n0 = h * 32 + lanelow, n1 = n0 + 16;
  int   orow_a[4][4];
  float r0a[4][4], r1a[4][4];
  #pragma unroll
  for (int qt = 0; qt < 4; ++qt)
    #pragma unroll
    for (int r = 0; r < 4; ++r) {
      int q = qt * 16 + quad * 4 + r;
      bool ok = (q < 49);
      int wrow = base + (ok ? q : 0);
      int orow = (OUT_SHIFT < 0) ? wrow : win_map(wrow, OUT_SHIFT);
      orow_a[qt][r] = orow;
      r0a[qt][r] = ok ? Rsrc[(size_t)orow * DIM + n0] : 0.f;
      r1a[qt][r] = ok ? Rsrc[(size_t)orow * DIM + n1] : 0.f;
    }

  // ---- S^T = K·Q^T (each wave reads only cols it wrote; barrier after reg loads) ----
  f32x4 sc[4][4];
  #pragma unroll
  for (int kt = 0; kt < 4; ++kt)
    #pragma unroll
    for (int qt = 0; qt < 4; ++qt) sc[kt][qt] = (f32x4){0.f, 0.f, 0.f, 0.f};
  {
    short8 kf[4], qf[4];
    const int kcol = 128 + h * 32 + quad * 8;
    const int qcol = h * 32 + quad * 8;
    #pragma unroll
    for (int t = 0; t < 4; ++t) {
      int tok = t * 16 + lanelow; if (tok > 48) tok = 48;
      kf[t] = *(const short8*)(qs + tok * QKV_STR + kcol);
      qf[t] = *(const short8*)(qs + tok * QKV_STR + qcol);
    }
    __syncthreads();   // all waves hold Q,K in regs; Q/K cols become dead -> P scratch
    #pragma unroll
    for (int kt = 0; kt < 4; ++kt)
      #pragma unroll
      for (int qt = 0; qt < 4; ++qt)
        sc[kt][qt] = __builtin_amdgcn_mfma_f32_16x16x32_bf16(kf[kt], qf[qt], sc[kt][qt], 0, 0, 0);
  }

  // ---- scale + bias + softmax over k ----
  const float* bh = biasT + h * 4096;
  #pragma unroll
  for (int kt = 0; kt < 4; ++kt)
    #pragma unroll
    for (int r = 0; r < 4; ++r) {
      const float* br = bh + (kt * 16 + quad * 4 + r) * 64 + lanelow;
      #pragma unroll
      for (int qt = 0; qt < 4; ++qt)
        sc[kt][qt][r] = fmaf(sc[kt][qt][r], 0.17677669529663689f, br[qt * 16]);
    }
  #pragma unroll
  for (int qt = 0; qt < 4; ++qt) {
    float m = sc[0][qt][0];
    #pragma unroll
    for (int kt = 0; kt < 4; ++kt)
      #pragma unroll
      for (int r = 0; r < 4; ++r) m = fmaxf(m, sc[kt][qt][r]);
    m = fmaxf(m, __shfl_xor(m, 16));
    m = fmaxf(m, __shfl_xor(m, 32));
    float s = 0.f;
    #pragma unroll
    for (int kt = 0; kt < 4; ++kt)
      #pragma unroll
      for (int r = 0; r < 4; ++r) {
        float e = __expf(sc[kt][qt][r] - m);
        sc[kt][qt][r] = e;
        s += e;
      }
    s += __shfl_xor(s, 16);
    s += __shfl_xor(s, 32);
    float inv = 1.0f / s;
    #pragma unroll
    for (int kt = 0; kt < 4; ++kt)
      #pragma unroll
      for (int r = 0; r < 4; ++r) sc[kt][qt][r] *= inv;
  }

  // ---- P (bf16) -> dead Q/K cols: P[q][k] at qs[q*STR + h*64 + k] ----
  uint16_t* pw = qs + h * 64;
  #pragma unroll
  for (int qt = 0; qt < 4; ++qt)
    #pragma unroll
    for (int kt = 0; kt < 4; ++kt) {
      uint2 pk;
      pk.x = bfpack(sc[kt][qt][0], sc[kt][qt][1]);
      pk.y = bfpack(sc[kt][qt][2], sc[kt][qt][3]);
      *(uint2*)(pw + (qt * 16 + lanelow) * QKV_STR + kt * 16 + quad * 4) = pk;
    }

  // ---- O = P·V ----
  f32x4 oc[4][2];
  #pragma unroll
  for (int qt = 0; qt < 4; ++qt)
    #pragma unroll
    for (int dt = 0; dt < 2; ++dt) oc[qt][dt] = (f32x4){0.f, 0.f, 0.f, 0.f};
  {
    short8 pf[4][2];
    #pragma unroll
    for (int qt = 0; qt < 4; ++qt)
      #pragma unroll
      for (int kp = 0; kp < 2; ++kp)
        pf[qt][kp] = *(const short8*)(pw + (qt * 16 + lanelow) * QKV_STR + kp * 32 + quad * 8);
    short8 vf[2][2];
    #pragma unroll
    for (int dt = 0; dt < 2; ++dt)
      #pragma unroll
      for (int kp = 0; kp < 2; ++kp) {
        short8 b;
        #pragma unroll
        for (int j = 0; j < 8; ++j) {
          int tok = kp * 32 + quad * 8 + j; if (tok > 48) tok = 48;
          b[j] = (short)qs[tok * QKV_STR + 256 + h * 32 + dt * 16 + lanelow];
        }
        vf[dt][kp] = b;
      }
    #pragma unroll
    for (int qt = 0; qt < 4; ++qt)
      #pragma unroll
      for (int dt = 0; dt < 2; ++dt)
        #pragma unroll
        for (int kp = 0; kp < 2; ++kp)
          oc[qt][dt] = __builtin_amdgcn_mfma_f32_16x16x32_bf16(pf[qt][kp], vf[dt][kp], oc[qt][dt], 0, 0, 0);
  }

  // ---- O -> LDS (alias flat over qs) ----
  __syncthreads();
  uint16_t* Os = qs;
  #pragma unroll
  for (int qt = 0; qt < 4; ++qt)
    #pragma unroll
    for (int r = 0; r < 4; ++r) {
      int t = qt * 16 + quad * 4 + r;
      #pragma unroll
      for (int dt = 0; dt < 2; ++dt)
        Os[t * OS_STR + h * 32 + dt * 16 + lanelow] = bf16of(oc[qt][dt][r]);
    }
  __syncthreads();

  // ---- proj: rc = O @ Wo^T, this wave computes cols h*32..h*32+31 ----
  f32x4 rc[4][2];
  #pragma unroll
  for (int qt = 0; qt < 4; ++qt)
    #pragma unroll
    for (int dt = 0; dt < 2; ++dt) rc[qt][dt] = (f32x4){0.f, 0.f, 0.f, 0.f};
  #pragma unroll
  for (int kp = 0; kp < 4; ++kp) {
    short8 af[4];
    #pragma unroll
    for (int qt = 0; qt < 4; ++qt)
      af[qt] = *(const short8*)&Os[(qt * 16 + lanelow) * OS_STR + kp * 32 + quad * 8];
    short8 bfr[2];
    #pragma unroll
    for (int dt = 0; dt < 2; ++dt)
      bfr[dt] = *(const short8*)(Wo + (size_t)(h * 32 + dt * 16 + lanelow) * DIM + kp * 32 + quad * 8);
    #pragma unroll
    for (int qt = 0; qt < 4; ++qt)
      #pragma unroll
      for (int dt = 0; dt < 2; ++dt)
        rc[qt][dt] = __builtin_amdgcn_mfma_f32_16x16x32_bf16(af[qt], bfr[dt], rc[qt][dt], 0, 0, 0);
  }

  // ---- bias + residual (prefetched) -> rc = x stream; attn-LN partials ----
  const float b0 = bo[n0], b1 = bo[n1];
  const float ga0 = lnga[n0], ga1 = lnga[n1];
  const float ea0 = lnba[n0], ea1 = lnba[n1];
  #pragma unroll
  for (int qt = 0; qt < 4; ++qt)
    #pragma unroll
    for (int r = 0; r < 4; ++r) {
      int q = qt * 16 + quad * 4 + r;
      float v0 = rc[qt][0][r] + b0 + r0a[qt][r];
      float v1 = rc[qt][1][r] + b1 + r1a[qt][r];
      rc[qt][0][r] = v0; rc[qt][1][r] = v1;
      float s = v0 + v1, sq = v0 * v0 + v1 * v1;
      s += __shfl_xor(s, 1); sq += __shfl_xor(sq, 1);
      s += __shfl_xor(s, 2); sq += __shfl_xor(sq, 2);
      s += __shfl_xor(s, 4); sq += __shfl_xor(sq, 4);
      s += __shfl_xor(s, 8); sq += __shfl_xor(sq, 8);
      if (lanelow == 0) { lnred[q][h][0] = s; lnred[q][h][1] = sq; }
    }
  __syncthreads();   // (A) lnred ready; all proj LDS reads complete -> Os region reusable

  // ---- attn-LN finalize -> normalized bf16 tile into X_lds (Os region) ----
  uint16_t* Xl = qs;
  #pragma unroll
  for (int qt = 0; qt < 4; ++qt)
    #pragma unroll
    for (int r = 0; r < 4; ++r) {
      int q = qt * 16 + quad * 4 + r;
      float s  = lnred[q][0][0] + lnred[q][1][0] + lnred[q][2][0] + lnred[q][3][0];
      float sq = lnred[q][0][1] + lnred[q][1][1] + lnred[q][2][1] + lnred[q][3][1];
      float mu = s * (1.0f / 128.0f);
      float rs = rsqrtf(sq * (1.0f / 128.0f) - mu * mu + 1e-5f);
      Xl[q * OS_STR + n0] = bf16of((rc[qt][0][r] - mu) * rs * ga0 + ea0);
      Xl[q * OS_STR + n1] = bf16of((rc[qt][1][r] - mu) * rs * ga1 + ea1);
    }
  __syncthreads();   // (B) normalized tile complete

  // ---- fused MLP GEMM: mc = norm @ Wm^T (this wave: cols n0, n1) ----
  f32x4 mc[4][2];
  #pragma unroll
  for (int qt = 0; qt < 4; ++qt)
    #pragma unroll
    for (int dt = 0; dt < 2; ++dt) mc[qt][dt] = (f32x4){0.f, 0.f, 0.f, 0.f};
  #pragma unroll
  for (int kp = 0; kp < 4; ++kp) {
    short8 af2[4];
    #pragma unroll
    for (int qt = 0; qt < 4; ++qt)
      af2[qt] = *(const short8*)&Xl[(qt * 16 + lanelow) * OS_STR + kp * 32 + quad * 8];
    short8 wfr[2];
    wfr[0] = *(const short8*)(Wm + (size_t)n0 * DIM + kp * 32 + quad * 8);
    wfr[1] = *(const short8*)(Wm + (size_t)n1 * DIM + kp * 32 + quad * 8);
    #pragma unroll
    for (int qt = 0; qt < 4; ++qt)
      #pragma unroll
      for (int dt = 0; dt < 2; ++dt)
        mc[qt][dt] = __builtin_amdgcn_mfma_f32_16x16x32_bf16(af2[qt], wfr[dt], mc[qt][dt], 0, 0, 0);
  }
  const float bm0 = bm[n0], bm1 = bm[n1];

  if constexpr (MLP_LN) {
    // x2 = x + mlp; post-mlp LN (ln3) partials (reuse lnred)
    const float gp0 = lngp[n0], gp1 = lngp[n1];
    const float ep0 = lnbp[n0], ep1 = lnbp[n1];
    #pragma unroll
    for (int qt = 0; qt < 4; ++qt)
      #pragma unroll
      for (int r = 0; r < 4; ++r) {
        int q = qt * 16 + quad * 4 + r;
        float v0 = rc[qt][0][r] + mc[qt][0][r] + bm0;
        float v1 = rc[qt][1][r] + mc[qt][1][r] + bm1;
        rc[qt][0][r] = v0; rc[qt][1][r] = v1;
        float s = v0 + v1, sq = v0 * v0 + v1 * v1;
        s += __shfl_xor(s, 1); sq += __shfl_xor(sq, 1);
        s += __shfl_xor(s, 2); sq += __shfl_xor(sq, 2);
        s += __shfl_xor(s, 4); sq += __shfl_xor(sq, 4);
        s += __shfl_xor(s, 8); sq += __shfl_xor(sq, 8);
        if (lanelow == 0) { lnred[q][h][0] = s; lnred[q][h][1] = sq; }
      }
    __syncthreads();   // (C)
    #pragma unroll
    for (int qt = 0; qt < 4; ++qt)
      #pragma unroll
      for (int r = 0; r < 4; ++r) {
        int q = qt * 16 + quad * 4 + r;
        if (q < 49) {
          int orow = orow_a[qt][r];
          float s  = lnred[q][0][0] + lnred[q][1][0] + lnred[q][2][0] + lnred[q][3][0];
          float sq = lnred[q][0][1] + lnred[q][1][1] + lnred[q][2][1] + lnred[q][3][1];
          float mu = s * (1.0f / 128.0f);
          float rs = rsqrtf(sq * (1.0f / 128.0f) - mu * mu + 1e-5f);
          float v0 = rc[qt][0][r], v1 = rc[qt][1][r];
          Xout[(size_t)orow * DIM + n0] = v0;
          Xout[(size_t)orow * DIM + n1] = v1;
          xbout[(size_t)orow * DIM + n0] = bf16of((v0 - mu) * rs * gp0 + ep0);
          xbout[(size_t)orow * DIM + n1] = bf16of((v1 - mu) * rs * gp1 + ep1);
        }
      }
  } else {
    // final mlp: out = mc + bm (no residual per source quirk), straight to Xout
    #pragma unroll
    for (int qt = 0; qt < 4; ++qt)
      #pragma unroll
      for (int r = 0; r < 4; ++r) {
        int q = qt * 16 + quad * 4 + r;
        if (q < 49) {
          int orow = orow_a[qt][r];
          Xout[(size_t)orow * DIM + n0] = mc[qt][0][r] + bm0;
          Xout[(size_t)orow * DIM + n1] = mc[qt][1][r] + bm1;
        }
      }
  }
}

extern "C" void kernel_launch(void* const* d_in, const int* in_sizes, int n_in,
                              void* d_out, int out_size, void* d_ws, size_t ws_size,
                              hipStream_t stream) {
  const float* x0    = (const float*)d_in[0];
  const float* ln1g  = (const float*)d_in[1];
  const float* ln1b  = (const float*)d_in[2];
  const float* wqkv1 = (const float*)d_in[3];
  const float* bqkv1 = (const float*)d_in[4];
  const float* wo1   = (const float*)d_in[5];
  const float* bo1   = (const float*)d_in[6];
  const float* tbl1  = (const float*)d_in[7];
  const float* ln2g  = (const float*)d_in[8];
  const float* ln2b  = (const float*)d_in[9];
  const float* wm1   = (const float*)d_in[10];
  const float* bm1   = (const float*)d_in[11];
  const float* ln3g  = (const float*)d_in[12];
  const float* ln3b  = (const float*)d_in[13];
  const float* wqkv2 = (const float*)d_in[14];
  const float* bqkv2 = (const float*)d_in[15];
  const float* wo2   = (const float*)d_in[16];
  const float* bo2   = (const float*)d_in[17];
  const float* tbl2  = (const float*)d_in[18];
  const float* ln4g  = (const float*)d_in[19];
  const float* ln4b  = (const float*)d_in[20];
  const float* wm2   = (const float*)d_in[21];
  const float* bm2   = (const float*)d_in[22];

  char* ws = (char*)d_ws;
  size_t off = 0;
  uint16_t* xbA  = (uint16_t*)(ws + off); off += (size_t)NTOK * 128 * sizeof(uint16_t);
  uint16_t* xb2  = (uint16_t*)(ws + off); off += (size_t)NTOK * 128 * sizeof(uint16_t);
  float* biasT1  = (float*)(ws + off);    off += 16384 * sizeof(float);
  float* biasT2  = (float*)(ws + off);    off += 16384 * sizeof(float);
  uint16_t* wb   = (uint16_t*)(ws + off); off += 163840 * sizeof(uint16_t);
  if (ws_size < off) return;
  float* x1 = (float*)d_out;   // f32 stream lives in d_out

  uint16_t* wqkv1b = wb;
  uint16_t* wqkv2b = wb + 49152;
  uint16_t* wo1b   = wb + 98304;
  uint16_t* wm1b   = wb + 114688;
  uint16_t* wo2b   = wb + 131072;
  uint16_t* wm2b   = wb + 147456;

  dim3 blk(256);
  dim3 lgrid(NTOK / 4);
  dim3 agrid(4096);

  wconv_k<<<640, blk, 0, stream>>>(wqkv1, wqkv2, wo1, wm1, wo2, wm2, wb);
  bias_k<<<64, blk, 0, stream>>>(tbl1, biasT1);
  bias_k<<<64, blk, 0, stream>>>(tbl2, biasT2);

  // ln1 -> xbA (spatial layout)
  ln_k<<<lgrid, blk, 0, stream>>>(x0, ln1g, ln1b, xbA);
  // block 1: W-MSA + proj + residual + ln2 + mlp1 + residual + ln3
  // reads xbA (spatial, via win_map shift 0); writes x1 (x2 stream) + xb2 (ln3 norm),
  // both at window-major rows (faithful identity-output quirk).
  attn4<0, -1, true><<<agrid, blk, 0, stream>>>(
      xbA, wqkv1b, bqkv1, biasT1, wo1b, bo1, x0, wm1b, bm1,
      ln2g, ln2b, ln3g, ln3b, x1, xb2);
  // block 2: SW-MSA + proj + residual + ln4 + mlp2 -> final output
  // reads xb2/x1 at win_map(.,3) rows; writes d_out at the same rows (bijective).
  attn4<3, 3, false><<<agrid, blk, 0, stream>>>(
      xb2, wqkv2b, bqkv2, biasT2, wo2b, bo2, x1, wm2b, bm2,
      ln4g, ln4b, ln4g, ln4b, x1, nullptr);
}